// Round 1
// baseline (2213.845 us; speedup 1.0000x reference)
//
#include <hip/hip_runtime.h>

#define D_MODEL 1024
#define D_FF    4096
#define NE      8
#define T_TOK   16384
#define MAXTILES 264
#define HOFF    (2u * 1024u * 1024u)

using frag_ab = __attribute__((ext_vector_type(8))) short;
using f32x4   = __attribute__((ext_vector_type(4))) float;
using ushort8 = __attribute__((ext_vector_type(8))) unsigned short;

__device__ __forceinline__ unsigned short f2bf(float f) {
  unsigned int u = __builtin_bit_cast(unsigned int, f);
  u += 0x7FFFu + ((u >> 16) & 1u);   // round-to-nearest-even
  return (unsigned short)(u >> 16);
}

__device__ __forceinline__ float gelu_f(float v) {
  return 0.5f * v * (1.0f + erff(v * 0.70710678118654752f));
}

// ---------------- Router: 1 wave per token, f64 logits, top-2 + softmax ----
__global__ void router_kernel(const float* __restrict__ x, const float* __restrict__ rw,
                              const float* __restrict__ rb, int* __restrict__ cnt,
                              int* __restrict__ tok, float* __restrict__ gat) {
  int gtid = blockIdx.x * blockDim.x + threadIdx.x;
  int t = gtid >> 6;
  int lane = threadIdx.x & 63;
  if (t >= T_TOK) return;
  const float* xr = x + (size_t)t * D_MODEL;
  double acc[NE];
#pragma unroll
  for (int e = 0; e < NE; ++e) acc[e] = 0.0;
  for (int j = lane; j < D_MODEL; j += 64) {
    double xv = (double)xr[j];
    const float* wr = rw + (size_t)j * NE;
#pragma unroll
    for (int e = 0; e < NE; ++e) acc[e] += xv * (double)wr[e];
  }
#pragma unroll
  for (int e = 0; e < NE; ++e) {
    double v = acc[e];
#pragma unroll
    for (int s = 32; s > 0; s >>= 1) v += __shfl_xor(v, s, 64);
    acc[e] = v;
  }
  if (lane == 0) {
    double lg[NE];
#pragma unroll
    for (int e = 0; e < NE; ++e) lg[e] = acc[e] + (double)rb[e];
    int b0 = 0; double v0 = lg[0];
#pragma unroll
    for (int e = 1; e < NE; ++e) if (lg[e] > v0) { v0 = lg[e]; b0 = e; }
    int b1 = -1; double v1 = -1.0e300;
#pragma unroll
    for (int e = 0; e < NE; ++e) if (e != b0 && lg[e] > v1) { v1 = lg[e]; b1 = e; }
    double g0 = 1.0 / (1.0 + exp(v1 - v0));
    int p0 = atomicAdd(&cnt[b0], 1);
    tok[b0 * T_TOK + p0] = t; gat[b0 * T_TOK + p0] = (float)g0;
    int p1 = atomicAdd(&cnt[b1], 1);
    tok[b1 * T_TOK + p1] = t; gat[b1 * T_TOK + p1] = (float)(1.0 - g0);
  }
}

// map flat tile slot -> (expert, local tile, n_e, padded H base row)
__device__ __forceinline__ int find_tile(const int* __restrict__ cnt, int slot,
                                         int& e, int& lt, int& ne, int& hb) {
  int tacc = 0, base = 0;
  for (int i = 0; i < NE; ++i) {
    int n = cnt[i];
    int tl = (n + 127) >> 7;
    if (slot < tacc + tl) { e = i; lt = slot - tacc; ne = n; hb = base; return 1; }
    tacc += tl; base += tl << 7;
  }
  return 0;
}

// ---------------- GEMM1: H = gelu(gather(x) @ w1[e] + b1[e]), bf16 out -----
__global__ __launch_bounds__(256) void gemm1_kernel(
    const float* __restrict__ x, const float* __restrict__ w1, const float* __restrict__ b1,
    const int* __restrict__ cnt, const int* __restrict__ tok,
    unsigned short* __restrict__ H, int ch, int FC) {
  __shared__ __align__(16) unsigned short As[128][40];
  __shared__ __align__(16) unsigned short Bs[128][40];
  int e, lt, ne, hb;
  if (!find_tile(cnt, blockIdx.x, e, lt, ne, hb)) return;
  int tid = threadIdx.x;
  int lane = tid & 63, wid = tid >> 6;
  int wr = wid >> 1, wc = wid & 1;
  int n0 = blockIdx.y * 128;     // column offset within this chunk
  f32x4 acc[4][4] = {};

  // A staging assignment: thread -> (row, 16-col half)
  int ar = tid >> 1;
  int ac0 = (tid & 1) * 16;
  int apos = lt * 128 + ar;
  int tokid = (apos < ne) ? tok[e * T_TOK + apos] : -1;
  const float* asrc = (tokid >= 0) ? (x + (size_t)tokid * D_MODEL + ac0) : x;

  // B staging assignment: thread -> (k row, 16-wide n group)
  int bkr = tid >> 3;
  int bng = (tid & 7) * 16;
  const float* bsrc = w1 + (size_t)e * D_MODEL * D_FF + (size_t)bkr * D_FF
                      + (size_t)(ch * FC + n0 + bng);

  for (int k0 = 0; k0 < D_MODEL; k0 += 32) {
    {
      ushort8 lo = {}, hi = {};
      if (tokid >= 0) {
        const float* s = asrc + k0;
#pragma unroll
        for (int i = 0; i < 8; ++i) lo[i] = f2bf(s[i]);
#pragma unroll
        for (int i = 0; i < 8; ++i) hi[i] = f2bf(s[8 + i]);
      }
      *(ushort8*)&As[ar][ac0] = lo;
      *(ushort8*)&As[ar][ac0 + 8] = hi;
    }
    {
      const float* s = bsrc + (size_t)k0 * D_FF;
#pragma unroll
      for (int i = 0; i < 16; i += 4) {
        float4 v = *(const float4*)(s + i);
        Bs[bng + i + 0][bkr] = f2bf(v.x);
        Bs[bng + i + 1][bkr] = f2bf(v.y);
        Bs[bng + i + 2][bkr] = f2bf(v.z);
        Bs[bng + i + 3][bkr] = f2bf(v.w);
      }
    }
    __syncthreads();
    int r16 = lane & 15, kg = lane >> 4;
    frag_ab a[4], b[4];
#pragma unroll
    for (int m = 0; m < 4; ++m) a[m] = *(const frag_ab*)&As[wr * 64 + m * 16 + r16][kg * 8];
#pragma unroll
    for (int n = 0; n < 4; ++n) b[n] = *(const frag_ab*)&Bs[wc * 64 + n * 16 + r16][kg * 8];
#pragma unroll
    for (int m = 0; m < 4; ++m)
#pragma unroll
      for (int n = 0; n < 4; ++n)
        acc[m][n] = __builtin_amdgcn_mfma_f32_16x16x32_bf16(a[m], b[n], acc[m][n], 0, 0, 0);
    __syncthreads();
  }

  int r16 = lane & 15, rg = lane >> 4;
  float b1v[4];
#pragma unroll
  for (int n = 0; n < 4; ++n)
    b1v[n] = b1[e * D_FF + ch * FC + n0 + wc * 64 + n * 16 + r16];
#pragma unroll
  for (int m = 0; m < 4; ++m) {
#pragma unroll
    for (int j = 0; j < 4; ++j) {
      int row = wr * 64 + m * 16 + rg * 4 + j;
      int grow = lt * 128 + row;
      size_t hrow = (size_t)(hb + grow) * (size_t)FC;
      bool valid = grow < ne;
#pragma unroll
      for (int n = 0; n < 4; ++n) {
        int col = n0 + wc * 64 + n * 16 + r16;
        float v = valid ? gelu_f(acc[m][n][j] + b1v[n]) : 0.0f;
        H[hrow + col] = f2bf(v);
      }
    }
  }
}

// ---------------- GEMM2: out += gate * (H @ w2[e] + b2[e]), atomic scatter --
__global__ __launch_bounds__(256) void gemm2_kernel(
    const unsigned short* __restrict__ H, const float* __restrict__ w2,
    const float* __restrict__ b2, const int* __restrict__ cnt,
    const int* __restrict__ tok, const float* __restrict__ gat,
    float* __restrict__ out, int ch, int FC) {
  __shared__ __align__(16) unsigned short As[128][40];
  __shared__ __align__(16) unsigned short Bs[128][40];
  int e, lt, ne, hb;
  if (!find_tile(cnt, blockIdx.x, e, lt, ne, hb)) return;
  int tid = threadIdx.x;
  int lane = tid & 63, wid = tid >> 6;
  int wr = wid >> 1, wc = wid & 1;
  int n0 = blockIdx.y * 128;
  f32x4 acc[4][4] = {};

  int ar = tid >> 1;
  int ac0 = (tid & 1) * 16;
  const unsigned short* asrc = H + (size_t)(hb + lt * 128 + ar) * (size_t)FC + ac0;

  int bkr = tid >> 3;
  int bng = (tid & 7) * 16;
  const float* bsrc = w2 + (size_t)e * D_FF * D_MODEL + (size_t)(ch * FC + bkr) * D_MODEL
                      + (size_t)(n0 + bng);

  for (int k0 = 0; k0 < FC; k0 += 32) {
    *(ushort8*)&As[ar][ac0]     = *(const ushort8*)(asrc + k0);
    *(ushort8*)&As[ar][ac0 + 8] = *(const ushort8*)(asrc + k0 + 8);
    {
      const float* s = bsrc + (size_t)k0 * D_MODEL;
#pragma unroll
      for (int i = 0; i < 16; i += 4) {
        float4 v = *(const float4*)(s + i);
        Bs[bng + i + 0][bkr] = f2bf(v.x);
        Bs[bng + i + 1][bkr] = f2bf(v.y);
        Bs[bng + i + 2][bkr] = f2bf(v.z);
        Bs[bng + i + 3][bkr] = f2bf(v.w);
      }
    }
    __syncthreads();
    int r16 = lane & 15, kg = lane >> 4;
    frag_ab a[4], b[4];
#pragma unroll
    for (int m = 0; m < 4; ++m) a[m] = *(const frag_ab*)&As[wr * 64 + m * 16 + r16][kg * 8];
#pragma unroll
    for (int n = 0; n < 4; ++n) b[n] = *(const frag_ab*)&Bs[wc * 64 + n * 16 + r16][kg * 8];
#pragma unroll
    for (int m = 0; m < 4; ++m)
#pragma unroll
      for (int n = 0; n < 4; ++n)
        acc[m][n] = __builtin_amdgcn_mfma_f32_16x16x32_bf16(a[m], b[n], acc[m][n], 0, 0, 0);
    __syncthreads();
  }

  int r16 = lane & 15, rg = lane >> 4;
  float b2v[4];
#pragma unroll
  for (int n = 0; n < 4; ++n)
    b2v[n] = (ch == 0) ? b2[e * D_MODEL + n0 + wc * 64 + n * 16 + r16] : 0.0f;
#pragma unroll
  for (int m = 0; m < 4; ++m) {
#pragma unroll
    for (int j = 0; j < 4; ++j) {
      int row = wr * 64 + m * 16 + rg * 4 + j;
      int grow = lt * 128 + row;
      if (grow < ne) {
        int tokid = tok[e * T_TOK + grow];
        float gate = gat[e * T_TOK + grow];
        float* orow = out + (size_t)tokid * D_MODEL + n0;
#pragma unroll
        for (int n = 0; n < 4; ++n) {
          int col = wc * 64 + n * 16 + r16;
          atomicAdd(&orow[col], gate * (acc[m][n][j] + b2v[n]));
        }
      }
    }
  }
}

extern "C" void kernel_launch(void* const* d_in, const int* in_sizes, int n_in,
                              void* d_out, int out_size, void* d_ws, size_t ws_size,
                              hipStream_t stream) {
  const float* x  = (const float*)d_in[0];
  const float* rw = (const float*)d_in[1];
  const float* rb = (const float*)d_in[2];
  const float* w1 = (const float*)d_in[3];
  const float* b1 = (const float*)d_in[4];
  const float* w2 = (const float*)d_in[5];
  const float* b2 = (const float*)d_in[6];
  float* out = (float*)d_out;
  char* ws = (char*)d_ws;

  int*   cnt = (int*)ws;
  int*   tok = (int*)(ws + 256);
  float* gat = (float*)(ws + 256 + (size_t)NE * T_TOK * 4);
  unsigned short* H = (unsigned short*)(ws + HOFF);

  // choose number of d_ff chunks so H (33792 padded rows x FC bf16) fits ws
  int nch = 1;
  while (nch < 32 && (size_t)HOFF + 33792ull * (size_t)(D_FF / nch) * 2ull > ws_size) nch <<= 1;
  int FC = D_FF / nch;

  hipMemsetAsync(cnt, 0, 64, stream);
  hipMemsetAsync(out, 0, (size_t)out_size * 4, stream);
  router_kernel<<<dim3(T_TOK / 4), dim3(256), 0, stream>>>(x, rw, rb, cnt, tok, gat);
  for (int ch = 0; ch < nch; ++ch) {
    gemm1_kernel<<<dim3(MAXTILES, FC / 128), dim3(256), 0, stream>>>(x, w1, b1, cnt, tok, H, ch, FC);
    gemm2_kernel<<<dim3(MAXTILES, D_MODEL / 128), dim3(256), 0, stream>>>(H, w2, b2, cnt, tok, gat, out, ch, FC);
  }
}

// Round 2
// 1494.679 us; speedup vs baseline: 1.4812x; 1.4812x over previous
//
#include <hip/hip_runtime.h>

#define D_MODEL 1024
#define D_FF    4096
#define NE      8
#define T_TOK   16384
#define MAXTILES 264
#define HOFF    (2u * 1024u * 1024u)

using frag_ab = __attribute__((ext_vector_type(8))) short;
using f32x4   = __attribute__((ext_vector_type(4))) float;
using ushort8 = __attribute__((ext_vector_type(8))) unsigned short;

__device__ __forceinline__ unsigned short f2bf(float f) {
  unsigned int u = __builtin_bit_cast(unsigned int, f);
  u += 0x7FFFu + ((u >> 16) & 1u);   // round-to-nearest-even
  return (unsigned short)(u >> 16);
}

__device__ __forceinline__ float gelu_f(float v) {
  return 0.5f * v * (1.0f + erff(v * 0.70710678118654752f));
}

__device__ __forceinline__ void gload16(const void* g, void* l) {
  __builtin_amdgcn_global_load_lds((const __attribute__((address_space(1))) void*)g,
                                   (__attribute__((address_space(3))) void*)l, 16, 0, 0);
}

// ---------------- Router: 1 wave per token, f64 logits, top-2 + softmax ----
__global__ void router_kernel(const float* __restrict__ x, const float* __restrict__ rw,
                              const float* __restrict__ rb, int* __restrict__ cnt,
                              int* __restrict__ tok, float* __restrict__ gat) {
  int gtid = blockIdx.x * blockDim.x + threadIdx.x;
  int t = gtid >> 6;
  int lane = threadIdx.x & 63;
  if (t >= T_TOK) return;
  const float* xr = x + (size_t)t * D_MODEL;
  double acc[NE];
#pragma unroll
  for (int e = 0; e < NE; ++e) acc[e] = 0.0;
  for (int j = lane; j < D_MODEL; j += 64) {
    double xv = (double)xr[j];
    const float* wr = rw + (size_t)j * NE;
#pragma unroll
    for (int e = 0; e < NE; ++e) acc[e] += xv * (double)wr[e];
  }
#pragma unroll
  for (int e = 0; e < NE; ++e) {
    double v = acc[e];
#pragma unroll
    for (int s = 32; s > 0; s >>= 1) v += __shfl_xor(v, s, 64);
    acc[e] = v;
  }
  if (lane == 0) {
    double lg[NE];
#pragma unroll
    for (int e = 0; e < NE; ++e) lg[e] = acc[e] + (double)rb[e];
    int b0 = 0; double v0 = lg[0];
#pragma unroll
    for (int e = 1; e < NE; ++e) if (lg[e] > v0) { v0 = lg[e]; b0 = e; }
    int b1 = -1; double v1 = -1.0e300;
#pragma unroll
    for (int e = 0; e < NE; ++e) if (e != b0 && lg[e] > v1) { v1 = lg[e]; b1 = e; }
    double g0 = 1.0 / (1.0 + exp(v1 - v0));
    int p0 = atomicAdd(&cnt[b0], 1);
    tok[b0 * T_TOK + p0] = t; gat[b0 * T_TOK + p0] = (float)g0;
    int p1 = atomicAdd(&cnt[b1], 1);
    tok[b1 * T_TOK + p1] = t; gat[b1 * T_TOK + p1] = (float)(1.0 - g0);
  }
}

// ---------------- Prepass: x f32 -> bf16 ------------------------------------
__global__ __launch_bounds__(256) void cvt_x_kernel(const float* __restrict__ x,
                                                    unsigned short* __restrict__ xb) {
  size_t i = ((size_t)blockIdx.x * 256 + threadIdx.x) * 8;
  float4 v0 = *(const float4*)(x + i);
  float4 v1 = *(const float4*)(x + i + 4);
  ushort8 o;
  o[0] = f2bf(v0.x); o[1] = f2bf(v0.y); o[2] = f2bf(v0.z); o[3] = f2bf(v0.w);
  o[4] = f2bf(v1.x); o[5] = f2bf(v1.y); o[6] = f2bf(v1.z); o[7] = f2bf(v1.w);
  *(ushort8*)(xb + i) = o;
}

// ---------------- Prepass: transpose+convert [E][R][C] f32 -> [E][C][R] bf16
__global__ __launch_bounds__(256) void transpose_cvt_kernel(const float* __restrict__ in,
                                                            unsigned short* __restrict__ out,
                                                            int R, int C) {
  __shared__ unsigned short tile[64][66];
  int e = blockIdx.z;
  int r0 = blockIdx.y * 64, c0 = blockIdx.x * 64;
  int t = threadIdx.x;
  int rr = t >> 4, cc = (t & 15) * 4;
  const float* src = in + ((size_t)e * R + r0) * C + c0;
#pragma unroll
  for (int p = 0; p < 4; ++p) {
    int r = rr + p * 16;
    float4 v = *(const float4*)(src + (size_t)r * C + cc);
    tile[r][cc + 0] = f2bf(v.x);
    tile[r][cc + 1] = f2bf(v.y);
    tile[r][cc + 2] = f2bf(v.z);
    tile[r][cc + 3] = f2bf(v.w);
  }
  __syncthreads();
  int oc = t >> 2, kc = (t & 3) * 16;
  ushort8 v0, v1;
#pragma unroll
  for (int i = 0; i < 8; ++i) v0[i] = tile[kc + i][oc];
#pragma unroll
  for (int i = 0; i < 8; ++i) v1[i] = tile[kc + 8 + i][oc];
  unsigned short* dst = out + ((size_t)e * C + c0 + oc) * R + r0 + kc;
  *(ushort8*)dst = v0;
  *(ushort8*)(dst + 8) = v1;
}

// map flat tile slot -> (expert, local tile, n_e, padded H base row)
__device__ __forceinline__ int find_tile(const int* __restrict__ cnt, int slot,
                                         int& e, int& lt, int& ne, int& hb) {
  int tacc = 0, base = 0;
  for (int i = 0; i < NE; ++i) {
    int n = cnt[i];
    int tl = (n + 127) >> 7;
    if (slot < tacc + tl) { e = i; lt = slot - tacc; ne = n; hb = base; return 1; }
    tacc += tl; base += tl << 7;
  }
  return 0;
}

// ---------------- GEMM1: H = gelu(gather(xb) @ w1t[e]^T + b1[e]), bf16 out --
// m97 structure: 128x128 tile, BK=32, linear LDS, global_load_lds width 16.
__global__ __launch_bounds__(256) void gemm1_kernel(
    const unsigned short* __restrict__ xb, const unsigned short* __restrict__ w1t,
    const float* __restrict__ b1, const int* __restrict__ cnt, const int* __restrict__ tok,
    unsigned short* __restrict__ H, int ch, int FC) {
  __shared__ __align__(16) unsigned short As[128][32];
  __shared__ __align__(16) unsigned short Bs[128][32];
  int e, lt, ne, hb;
  if (!find_tile(cnt, blockIdx.x, e, lt, ne, hb)) return;
  int tid = threadIdx.x;
  int lane = tid & 63, w = tid >> 6;
  int wr = w >> 1, wc = w & 1;
  int n0 = blockIdx.y * 128;
  f32x4 acc[4][4] = {};

  // staging: chunk c (16B) -> row c>>2, k8 (c&3)*8 ; chunk = (issue*4+w)*64+lane
  int srow = w * 16 + (lane >> 2);           // rows for issue 0; +64 for issue 1
  int sk8  = (lane & 3) * 8;
  int g0 = lt * 128 + srow, g1 = g0 + 64;
  const unsigned short* asrc0 = xb + (size_t)((g0 < ne) ? tok[e * T_TOK + g0] : 0) * D_MODEL + sk8;
  const unsigned short* asrc1 = xb + (size_t)((g1 < ne) ? tok[e * T_TOK + g1] : 0) * D_MODEL + sk8;
  const unsigned short* bsrc0 = w1t + ((size_t)e * D_FF + ch * FC + n0 + srow) * D_MODEL + sk8;
  const unsigned short* bsrc1 = bsrc0 + (size_t)64 * D_MODEL;
  char* aldst0 = (char*)As + w * 1024; char* aldst1 = aldst0 + 4096;
  char* bldst0 = (char*)Bs + w * 1024; char* bldst1 = bldst0 + 4096;

  for (int k0 = 0; k0 < D_MODEL; k0 += 32) {
    gload16(asrc0 + k0, aldst0);
    gload16(asrc1 + k0, aldst1);
    gload16(bsrc0 + k0, bldst0);
    gload16(bsrc1 + k0, bldst1);
    __syncthreads();
    int r16 = lane & 15, kg = lane >> 4;
    frag_ab a[4], b[4];
#pragma unroll
    for (int m = 0; m < 4; ++m) a[m] = *(const frag_ab*)&As[wr * 64 + m * 16 + r16][kg * 8];
#pragma unroll
    for (int n = 0; n < 4; ++n) b[n] = *(const frag_ab*)&Bs[wc * 64 + n * 16 + r16][kg * 8];
#pragma unroll
    for (int m = 0; m < 4; ++m)
#pragma unroll
      for (int n = 0; n < 4; ++n)
        acc[m][n] = __builtin_amdgcn_mfma_f32_16x16x32_bf16(a[m], b[n], acc[m][n], 0, 0, 0);
    __syncthreads();
  }

  int r16 = lane & 15, rg = lane >> 4;
  float b1v[4];
#pragma unroll
  for (int n = 0; n < 4; ++n)
    b1v[n] = b1[e * D_FF + ch * FC + n0 + wc * 64 + n * 16 + r16];
#pragma unroll
  for (int m = 0; m < 4; ++m) {
#pragma unroll
    for (int j = 0; j < 4; ++j) {
      int row = wr * 64 + m * 16 + rg * 4 + j;
      int grow = lt * 128 + row;
      size_t hrow = (size_t)(hb + grow) * (size_t)FC;
#pragma unroll
      for (int n = 0; n < 4; ++n) {
        int col = n0 + wc * 64 + n * 16 + r16;
        H[hrow + col] = f2bf(gelu_f(acc[m][n][j] + b1v[n]));
      }
    }
  }
}

// ---------------- GEMM2: out += gate * (H @ w2t[e]^T + b2[e]), atomic -------
__global__ __launch_bounds__(256) void gemm2_kernel(
    const unsigned short* __restrict__ H, const unsigned short* __restrict__ w2t,
    const float* __restrict__ b2, const int* __restrict__ cnt,
    const int* __restrict__ tok, const float* __restrict__ gat,
    float* __restrict__ out, int ch, int FC) {
  __shared__ __align__(16) unsigned short As[128][32];
  __shared__ __align__(16) unsigned short Bs[128][32];
  int e, lt, ne, hb;
  if (!find_tile(cnt, blockIdx.x, e, lt, ne, hb)) return;
  int tid = threadIdx.x;
  int lane = tid & 63, w = tid >> 6;
  int wr = w >> 1, wc = w & 1;
  int n0 = blockIdx.y * 128;
  f32x4 acc[4][4] = {};

  int srow = w * 16 + (lane >> 2);
  int sk8  = (lane & 3) * 8;
  const unsigned short* asrc0 = H + (size_t)(hb + lt * 128 + srow) * FC + sk8;
  const unsigned short* asrc1 = asrc0 + (size_t)64 * FC;
  const unsigned short* bsrc0 = w2t + ((size_t)e * D_MODEL + n0 + srow) * D_FF + ch * FC + sk8;
  const unsigned short* bsrc1 = bsrc0 + (size_t)64 * D_FF;
  char* aldst0 = (char*)As + w * 1024; char* aldst1 = aldst0 + 4096;
  char* bldst0 = (char*)Bs + w * 1024; char* bldst1 = bldst0 + 4096;

  for (int k0 = 0; k0 < FC; k0 += 32) {
    gload16(asrc0 + k0, aldst0);
    gload16(asrc1 + k0, aldst1);
    gload16(bsrc0 + k0, bldst0);
    gload16(bsrc1 + k0, bldst1);
    __syncthreads();
    int r16 = lane & 15, kg = lane >> 4;
    frag_ab a[4], b[4];
#pragma unroll
    for (int m = 0; m < 4; ++m) a[m] = *(const frag_ab*)&As[wr * 64 + m * 16 + r16][kg * 8];
#pragma unroll
    for (int n = 0; n < 4; ++n) b[n] = *(const frag_ab*)&Bs[wc * 64 + n * 16 + r16][kg * 8];
#pragma unroll
    for (int m = 0; m < 4; ++m)
#pragma unroll
      for (int n = 0; n < 4; ++n)
        acc[m][n] = __builtin_amdgcn_mfma_f32_16x16x32_bf16(a[m], b[n], acc[m][n], 0, 0, 0);
    __syncthreads();
  }

  int r16 = lane & 15, rg = lane >> 4;
  float b2v[4];
#pragma unroll
  for (int n = 0; n < 4; ++n)
    b2v[n] = (ch == 0) ? b2[e * D_MODEL + n0 + wc * 64 + n * 16 + r16] : 0.0f;
#pragma unroll
  for (int m = 0; m < 4; ++m) {
#pragma unroll
    for (int j = 0; j < 4; ++j) {
      int row = wr * 64 + m * 16 + rg * 4 + j;
      int grow = lt * 128 + row;
      if (grow < ne) {
        int tokid = tok[e * T_TOK + grow];
        float gate = gat[e * T_TOK + grow];
        float* orow = out + (size_t)tokid * D_MODEL + n0;
#pragma unroll
        for (int n = 0; n < 4; ++n) {
          int col = wc * 64 + n * 16 + r16;
          atomicAdd(&orow[col], gate * (acc[m][n][j] + b2v[n]));
        }
      }
    }
  }
}

extern "C" void kernel_launch(void* const* d_in, const int* in_sizes, int n_in,
                              void* d_out, int out_size, void* d_ws, size_t ws_size,
                              hipStream_t stream) {
  const float* x  = (const float*)d_in[0];
  const float* rw = (const float*)d_in[1];
  const float* rb = (const float*)d_in[2];
  const float* w1 = (const float*)d_in[3];
  const float* b1 = (const float*)d_in[4];
  const float* w2 = (const float*)d_in[5];
  const float* b2 = (const float*)d_in[6];
  float* out = (float*)d_out;
  char* ws = (char*)d_ws;

  int*   cnt = (int*)ws;
  int*   tok = (int*)(ws + 256);
  float* gat = (float*)(ws + 256 + (size_t)NE * T_TOK * 4);

  size_t off = HOFF;
  unsigned short* xb  = (unsigned short*)(ws + off); off += (size_t)T_TOK * D_MODEL * 2;
  unsigned short* w1t = (unsigned short*)(ws + off); off += (size_t)NE * D_MODEL * D_FF * 2;
  unsigned short* w2t = (unsigned short*)(ws + off); off += (size_t)NE * D_MODEL * D_FF * 2;
  unsigned short* H   = (unsigned short*)(ws + off);

  // choose number of d_ff chunks so H (33792 padded rows x FC bf16) fits ws
  int nch = 1;
  while (nch < 32 && off + 33792ull * (size_t)(D_FF / nch) * 2ull > ws_size) nch <<= 1;
  int FC = D_FF / nch;

  hipMemsetAsync(cnt, 0, 64, stream);
  hipMemsetAsync(out, 0, (size_t)out_size * 4, stream);
  cvt_x_kernel<<<dim3(T_TOK * D_MODEL / 2048), dim3(256), 0, stream>>>(x, xb);
  transpose_cvt_kernel<<<dim3(D_FF / 64, D_MODEL / 64, NE), dim3(256), 0, stream>>>(w1, w1t, D_MODEL, D_FF);
  transpose_cvt_kernel<<<dim3(D_MODEL / 64, D_FF / 64, NE), dim3(256), 0, stream>>>(w2, w2t, D_FF, D_MODEL);
  router_kernel<<<dim3(T_TOK / 4), dim3(256), 0, stream>>>(x, rw, rb, cnt, tok, gat);
  for (int ch = 0; ch < nch; ++ch) {
    gemm1_kernel<<<dim3(MAXTILES, FC / 128), dim3(256), 0, stream>>>(xb, w1t, b1, cnt, tok, H, ch, FC);
    gemm2_kernel<<<dim3(MAXTILES, D_MODEL / 128), dim3(256), 0, stream>>>(H, w2t, b2, cnt, tok, gat, out, ch, FC);
  }
}

// Round 3
// 1378.297 us; speedup vs baseline: 1.6062x; 1.0844x over previous
//
#include <hip/hip_runtime.h>

#define D_MODEL 1024
#define D_FF    4096
#define NE      8
#define T_TOK   16384
#define MAXT    136
#define HOFF    (2u * 1024u * 1024u)

using frag_ab = __attribute__((ext_vector_type(8))) short;
using f32x4   = __attribute__((ext_vector_type(4))) float;
using ushort8 = __attribute__((ext_vector_type(8))) unsigned short;

__device__ __forceinline__ unsigned short f2bf(float f) {
  unsigned int u = __builtin_bit_cast(unsigned int, f);
  u += 0x7FFFu + ((u >> 16) & 1u);   // round-to-nearest-even
  return (unsigned short)(u >> 16);
}

__device__ __forceinline__ float gelu_f(float v) {
  return 0.5f * v * (1.0f + erff(v * 0.70710678118654752f));
}

__device__ __forceinline__ void gload16(const void* g, void* l) {
  __builtin_amdgcn_global_load_lds((const __attribute__((address_space(1))) void*)g,
                                   (__attribute__((address_space(3))) void*)l, 16, 0, 0);
}

#define FENCE __builtin_amdgcn_sched_barrier(0)
#define BARRIER do { FENCE; __builtin_amdgcn_s_barrier(); FENCE; } while (0)
__device__ __forceinline__ void waitv(int n) {
  if (n == 6) asm volatile("s_waitcnt vmcnt(6)" ::: "memory");
  else        asm volatile("s_waitcnt vmcnt(0)" ::: "memory");
}

// ---------------- Router: 1 wave per token, f64 logits, top-2 + softmax ----
__global__ void router_kernel(const float* __restrict__ x, const float* __restrict__ rw,
                              const float* __restrict__ rb, int* __restrict__ cnt,
                              int* __restrict__ tok, float* __restrict__ gat) {
  int gtid = blockIdx.x * blockDim.x + threadIdx.x;
  int t = gtid >> 6;
  int lane = threadIdx.x & 63;
  if (t >= T_TOK) return;
  const float* xr = x + (size_t)t * D_MODEL;
  double acc[NE];
#pragma unroll
  for (int e = 0; e < NE; ++e) acc[e] = 0.0;
  for (int j = lane; j < D_MODEL; j += 64) {
    double xv = (double)xr[j];
    const float* wr = rw + (size_t)j * NE;
#pragma unroll
    for (int e = 0; e < NE; ++e) acc[e] += xv * (double)wr[e];
  }
#pragma unroll
  for (int e = 0; e < NE; ++e) {
    double v = acc[e];
#pragma unroll
    for (int s = 32; s > 0; s >>= 1) v += __shfl_xor(v, s, 64);
    acc[e] = v;
  }
  if (lane == 0) {
    double lg[NE];
#pragma unroll
    for (int e = 0; e < NE; ++e) lg[e] = acc[e] + (double)rb[e];
    int b0 = 0; double v0 = lg[0];
#pragma unroll
    for (int e = 1; e < NE; ++e) if (lg[e] > v0) { v0 = lg[e]; b0 = e; }
    int b1 = -1; double v1 = -1.0e300;
#pragma unroll
    for (int e = 0; e < NE; ++e) if (e != b0 && lg[e] > v1) { v1 = lg[e]; b1 = e; }
    double g0 = 1.0 / (1.0 + exp(v1 - v0));
    int p0 = atomicAdd(&cnt[b0], 1);
    tok[b0 * T_TOK + p0] = t; gat[b0 * T_TOK + p0] = (float)g0;
    int p1 = atomicAdd(&cnt[b1], 1);
    tok[b1 * T_TOK + p1] = t; gat[b1 * T_TOK + p1] = (float)(1.0 - g0);
  }
}

// ---------------- Prepass: x f32 -> bf16 ------------------------------------
__global__ __launch_bounds__(256) void cvt_x_kernel(const float* __restrict__ x,
                                                    unsigned short* __restrict__ xb) {
  size_t i = ((size_t)blockIdx.x * 256 + threadIdx.x) * 8;
  float4 v0 = *(const float4*)(x + i);
  float4 v1 = *(const float4*)(x + i + 4);
  ushort8 o;
  o[0] = f2bf(v0.x); o[1] = f2bf(v0.y); o[2] = f2bf(v0.z); o[3] = f2bf(v0.w);
  o[4] = f2bf(v1.x); o[5] = f2bf(v1.y); o[6] = f2bf(v1.z); o[7] = f2bf(v1.w);
  *(ushort8*)(xb + i) = o;
}

// ---------------- Prepass: transpose+convert [E][R][C] f32 -> [E][C][R] bf16
__global__ __launch_bounds__(256) void transpose_cvt_kernel(const float* __restrict__ in,
                                                            unsigned short* __restrict__ out,
                                                            int R, int C) {
  __shared__ unsigned short tile[64][66];
  int e = blockIdx.z;
  int r0 = blockIdx.y * 64, c0 = blockIdx.x * 64;
  int t = threadIdx.x;
  int rr = t >> 4, cc = (t & 15) * 4;
  const float* src = in + ((size_t)e * R + r0) * C + c0;
#pragma unroll
  for (int p = 0; p < 4; ++p) {
    int r = rr + p * 16;
    float4 v = *(const float4*)(src + (size_t)r * C + cc);
    tile[r][cc + 0] = f2bf(v.x);
    tile[r][cc + 1] = f2bf(v.y);
    tile[r][cc + 2] = f2bf(v.z);
    tile[r][cc + 3] = f2bf(v.w);
  }
  __syncthreads();
  int oc = t >> 2, kc = (t & 3) * 16;
  ushort8 v0, v1;
#pragma unroll
  for (int i = 0; i < 8; ++i) v0[i] = tile[kc + i][oc];
#pragma unroll
  for (int i = 0; i < 8; ++i) v1[i] = tile[kc + 8 + i][oc];
  unsigned short* dst = out + ((size_t)e * C + c0 + oc) * R + r0 + kc;
  *(ushort8*)dst = v0;
  *(ushort8*)(dst + 8) = v1;
}

// map flat 256-row tile slot -> (expert, local tile, n_e, padded H base row)
__device__ __forceinline__ int find_tile256(const int* __restrict__ cnt, int slot,
                                            int& e, int& lt, int& ne, int& hb) {
  int tacc = 0, base = 0;
  for (int i = 0; i < NE; ++i) {
    int n = cnt[i];
    int tl = (n + 255) >> 8;
    if (slot < tacc + tl) { e = i; lt = slot - tacc; ne = n; hb = base; return 1; }
    tacc += tl; base += tl << 8;
  }
  return 0;
}

// ===================== 256x256x64 8-phase GEMM kernels ======================
// LDS: buf b at b*65536; A tile [256 rows][64 k] at +0, B tile at +32768.
// Chunk swizzle: LDS slot (row, c8) holds global k-chunk (c8 ^ (row&7)).

#define STG_A(qa, kt, b) do { \
    gload16(pA##qa##0 + (size_t)(kt) * 64, ldsp + (b) * 65536 + dA + (qa) * 8192); \
    gload16(pA##qa##1 + (size_t)(kt) * 64, ldsp + (b) * 65536 + dA + (qa) * 8192 + 16384); \
  } while (0)
#define STG_B(qb, kt, b) do { \
    gload16(pB##qb##0 + (size_t)(kt) * 64, ldsp + (b) * 65536 + 32768 + dB + (qb) * 4096); \
    gload16(pB##qb##1 + (size_t)(kt) * 64, ldsp + (b) * 65536 + 32768 + dB + (qb) * 4096 + 16384); \
  } while (0)

#define GEMM_BODY(NTILES)                                                        \
  f32x4 acc[8][4] = {};                                                          \
  frag_ab a[4][2], bb[4][2];                                                     \
  const int NT = (NTILES);                                                       \
  /* prologue: tile0 all 4 units, tile1 first 3 */                               \
  STG_A(0, 0, 0); STG_B(0, 0, 0); STG_B(1, 0, 0); STG_A(1, 0, 0);                \
  STG_A(0, 1, 1); STG_B(0, 1, 1); STG_B(1, 1, 1);                                \
  waitv(6); BARRIER;                                                             \
  for (int t = 0; t < NT; ++t) {                                                 \
    const char* AB = ldsp + (t & 1) * 65536;                                     \
    /* ---- p0: read A-q0 + B-q0; stage (t+1, A-q1) ---- */                      \
    _Pragma("unroll") for (int i = 0; i < 4; ++i) {                              \
      a[i][0] = *(const frag_ab*)(AB + aoff + i * 2048 + xs0);                   \
      a[i][1] = *(const frag_ab*)(AB + aoff + i * 2048 + xs1);                   \
    }                                                                            \
    _Pragma("unroll") for (int j = 0; j < 2; ++j) {                              \
      bb[j][0] = *(const frag_ab*)(AB + boff + j * 2048 + xs0);                  \
      bb[j][1] = *(const frag_ab*)(AB + boff + j * 2048 + xs1);                  \
    }                                                                            \
    if (t + 1 < NT) STG_A(1, t + 1, (t + 1) & 1);                                \
    BARRIER;                                                                     \
    __builtin_amdgcn_s_setprio(1);                                               \
    _Pragma("unroll") for (int i = 0; i < 4; ++i)                                \
      _Pragma("unroll") for (int j = 0; j < 2; ++j) {                            \
        acc[i][j] = __builtin_amdgcn_mfma_f32_16x16x32_bf16(a[i][0], bb[j][0], acc[i][j], 0, 0, 0); \
        acc[i][j] = __builtin_amdgcn_mfma_f32_16x16x32_bf16(a[i][1], bb[j][1], acc[i][j], 0, 0, 0); \
      }                                                                          \
    __builtin_amdgcn_s_setprio(0);                                               \
    BARRIER;                                                                     \
    /* ---- p1: read B-q1; stage (t+2, A-q0) ---- */                             \
    _Pragma("unroll") for (int j = 0; j < 2; ++j) {                              \
      bb[2 + j][0] = *(const frag_ab*)(AB + boff + (2 + j) * 2048 + xs0);        \
      bb[2 + j][1] = *(const frag_ab*)(AB + boff + (2 + j) * 2048 + xs1);        \
    }                                                                            \
    if (t + 2 < NT) STG_A(0, t + 2, t & 1);                                      \
    BARRIER;                                                                     \
    __builtin_amdgcn_s_setprio(1);                                               \
    _Pragma("unroll") for (int i = 0; i < 4; ++i)                                \
      _Pragma("unroll") for (int j = 0; j < 2; ++j) {                            \
        acc[i][2 + j] = __builtin_amdgcn_mfma_f32_16x16x32_bf16(a[i][0], bb[2 + j][0], acc[i][2 + j], 0, 0, 0); \
        acc[i][2 + j] = __builtin_amdgcn_mfma_f32_16x16x32_bf16(a[i][1], bb[2 + j][1], acc[i][2 + j], 0, 0, 0); \
      }                                                                          \
    __builtin_amdgcn_s_setprio(0);                                               \
    BARRIER;                                                                     \
    /* ---- p2: read A-q1; stage (t+2, B-q0) ---- */                             \
    _Pragma("unroll") for (int i = 0; i < 4; ++i) {                              \
      a[i][0] = *(const frag_ab*)(AB + aoff + 8192 + i * 2048 + xs0);            \
      a[i][1] = *(const frag_ab*)(AB + aoff + 8192 + i * 2048 + xs1);            \
    }                                                                            \
    if (t + 2 < NT) STG_B(0, t + 2, t & 1);                                      \
    BARRIER;                                                                     \
    __builtin_amdgcn_s_setprio(1);                                               \
    _Pragma("unroll") for (int i = 0; i < 4; ++i)                                \
      _Pragma("unroll") for (int j = 0; j < 2; ++j) {                            \
        acc[4 + i][2 + j] = __builtin_amdgcn_mfma_f32_16x16x32_bf16(a[i][0], bb[2 + j][0], acc[4 + i][2 + j], 0, 0, 0); \
        acc[4 + i][2 + j] = __builtin_amdgcn_mfma_f32_16x16x32_bf16(a[i][1], bb[2 + j][1], acc[4 + i][2 + j], 0, 0, 0); \
      }                                                                          \
    __builtin_amdgcn_s_setprio(0);                                               \
    BARRIER;                                                                     \
    /* ---- p3: no reads; stage (t+2, B-q1); boundary vmcnt ---- */              \
    if (t + 2 < NT) STG_B(1, t + 2, t & 1);                                      \
    BARRIER;                                                                     \
    __builtin_amdgcn_s_setprio(1);                                               \
    _Pragma("unroll") for (int i = 0; i < 4; ++i)                                \
      _Pragma("unroll") for (int j = 0; j < 2; ++j) {                            \
        acc[4 + i][j] = __builtin_amdgcn_mfma_f32_16x16x32_bf16(a[i][0], bb[j][0], acc[4 + i][j], 0, 0, 0); \
        acc[4 + i][j] = __builtin_amdgcn_mfma_f32_16x16x32_bf16(a[i][1], bb[j][1], acc[4 + i][j], 0, 0, 0); \
      }                                                                          \
    __builtin_amdgcn_s_setprio(0);                                               \
    waitv((t + 2 < NT) ? 6 : 0);                                                 \
    BARRIER;                                                                     \
  }

// ---------------- GEMM1: H = gelu(gather(xb) @ w1t[e]^T + b1[e]) ------------
__global__ __launch_bounds__(512, 2) void gemm1_kernel(
    const unsigned short* __restrict__ xb, const unsigned short* __restrict__ w1t,
    const float* __restrict__ b1, const int* __restrict__ cnt, const int* __restrict__ tok,
    unsigned short* __restrict__ H, int ch, int FC) {
  __shared__ __align__(16) char lds[131072];
  int e, lt, ne, hb;
  if (!find_tile256(cnt, blockIdx.x, e, lt, ne, hb)) return;
  char* ldsp = (char*)lds;
  const int tid = threadIdx.x;
  const int lane = tid & 63, w = tid >> 6;
  const int wm = w >> 2, wn = w & 3;
  const int r16 = lane & 15, kg = lane >> 4;
  const int n0 = blockIdx.y * 256;
  const int chn0 = ch * FC + n0;

  const int xs0 = (kg ^ (r16 & 7)) * 16;
  const int xs1 = ((4 + kg) ^ (r16 & 7)) * 16;
  const int aoff = (wm * 128 + r16) * 128;
  const int boff = 32768 + (wn * 64 + r16) * 128;

  // staging geometry
  const int v = w * 8 + (lane >> 3);
  const int c8off = ((lane & 7) ^ ((lane >> 3) & 7)) * 8;
  const int dA = w * 1024;
  const int dB = (w & 3) * 1024 + (w >> 2) * 8192;
  const int tokbase = e * T_TOK;
  // A rows (gathered tokens)
  int rA00 = v, rA01 = v + 128, rA10 = 64 + v, rA11 = 192 + v;
  int g00 = lt * 256 + rA00, g01 = lt * 256 + rA01, g10 = lt * 256 + rA10, g11 = lt * 256 + rA11;
  int tk00 = tok[tokbase + ((g00 < ne) ? g00 : 0)];
  int tk01 = tok[tokbase + ((g01 < ne) ? g01 : 0)];
  int tk10 = tok[tokbase + ((g10 < ne) ? g10 : 0)];
  int tk11 = tok[tokbase + ((g11 < ne) ? g11 : 0)];
  const unsigned short* pA00 = xb + (size_t)tk00 * D_MODEL + c8off;
  const unsigned short* pA01 = xb + (size_t)tk01 * D_MODEL + c8off;
  const unsigned short* pA10 = xb + (size_t)tk10 * D_MODEL + c8off;
  const unsigned short* pA11 = xb + (size_t)tk11 * D_MODEL + c8off;
  // B rows (w1t: [E][D_FF][D_MODEL])
  int rB00 = (v & 31) + (v >> 5) * 64;
  int rB01 = rB00 + 128, rB10 = rB00 + 32, rB11 = rB00 + 160;
  const unsigned short* pB00 = w1t + ((size_t)e * D_FF + chn0 + rB00) * D_MODEL + c8off;
  const unsigned short* pB01 = w1t + ((size_t)e * D_FF + chn0 + rB01) * D_MODEL + c8off;
  const unsigned short* pB10 = w1t + ((size_t)e * D_FF + chn0 + rB10) * D_MODEL + c8off;
  const unsigned short* pB11 = w1t + ((size_t)e * D_FF + chn0 + rB11) * D_MODEL + c8off;

  GEMM_BODY(D_MODEL / 64)

  float b1v[4];
#pragma unroll
  for (int j = 0; j < 4; ++j)
    b1v[j] = b1[e * D_FF + chn0 + wn * 64 + j * 16 + r16];
#pragma unroll
  for (int i = 0; i < 8; ++i) {
#pragma unroll
    for (int jj = 0; jj < 4; ++jj) {
      int row = wm * 128 + i * 16 + kg * 4 + jj;
      size_t hrow = (size_t)(hb + lt * 256 + row) * (size_t)FC;
#pragma unroll
      for (int j = 0; j < 4; ++j) {
        int col = n0 + wn * 64 + j * 16 + r16;
        H[hrow + col] = f2bf(gelu_f(acc[i][j][jj] + b1v[j]));
      }
    }
  }
}

// ---------------- GEMM2: out += gate * (H @ w2t[e]^T + b2[e]), atomic -------
__global__ __launch_bounds__(512, 2) void gemm2_kernel(
    const unsigned short* __restrict__ H, const unsigned short* __restrict__ w2t,
    const float* __restrict__ b2, const int* __restrict__ cnt,
    const int* __restrict__ tok, const float* __restrict__ gat,
    float* __restrict__ out, int ch, int FC) {
  __shared__ __align__(16) char lds[131072];
  int e, lt, ne, hb;
  if (!find_tile256(cnt, blockIdx.x, e, lt, ne, hb)) return;
  char* ldsp = (char*)lds;
  const int tid = threadIdx.x;
  const int lane = tid & 63, w = tid >> 6;
  const int wm = w >> 2, wn = w & 3;
  const int r16 = lane & 15, kg = lane >> 4;
  const int n0 = blockIdx.y * 256;

  const int xs0 = (kg ^ (r16 & 7)) * 16;
  const int xs1 = ((4 + kg) ^ (r16 & 7)) * 16;
  const int aoff = (wm * 128 + r16) * 128;
  const int boff = 32768 + (wn * 64 + r16) * 128;

  const int v = w * 8 + (lane >> 3);
  const int c8off = ((lane & 7) ^ ((lane >> 3) & 7)) * 8;
  const int dA = w * 1024;
  const int dB = (w & 3) * 1024 + (w >> 2) * 8192;
  const int tokbase = e * T_TOK;
  // A rows from H (padded rows exist and hold junk; masked at epilogue)
  int rA00 = v, rA01 = v + 128, rA10 = 64 + v, rA11 = 192 + v;
  const unsigned short* pA00 = H + (size_t)(hb + lt * 256 + rA00) * FC + c8off;
  const unsigned short* pA01 = H + (size_t)(hb + lt * 256 + rA01) * FC + c8off;
  const unsigned short* pA10 = H + (size_t)(hb + lt * 256 + rA10) * FC + c8off;
  const unsigned short* pA11 = H + (size_t)(hb + lt * 256 + rA11) * FC + c8off;
  // B rows (w2t: [E][D_MODEL][D_FF]); K offset = ch*FC + kt*64
  int rB00 = (v & 31) + (v >> 5) * 64;
  int rB01 = rB00 + 128, rB10 = rB00 + 32, rB11 = rB00 + 160;
  const unsigned short* pB00 = w2t + ((size_t)e * D_MODEL + n0 + rB00) * D_FF + (size_t)ch * FC + c8off;
  const unsigned short* pB01 = w2t + ((size_t)e * D_MODEL + n0 + rB01) * D_FF + (size_t)ch * FC + c8off;
  const unsigned short* pB10 = w2t + ((size_t)e * D_MODEL + n0 + rB10) * D_FF + (size_t)ch * FC + c8off;
  const unsigned short* pB11 = w2t + ((size_t)e * D_MODEL + n0 + rB11) * D_FF + (size_t)ch * FC + c8off;

  GEMM_BODY(FC / 64)

  float b2v[4];
#pragma unroll
  for (int j = 0; j < 4; ++j)
    b2v[j] = (ch == 0) ? b2[e * D_MODEL + n0 + wn * 64 + j * 16 + r16] : 0.0f;
#pragma unroll
  for (int i = 0; i < 8; ++i) {
#pragma unroll
    for (int jj = 0; jj < 4; ++jj) {
      int row = wm * 128 + i * 16 + kg * 4 + jj;
      int grow = lt * 256 + row;
      if (grow < ne) {
        int tokid = tok[tokbase + grow];
        float gate = gat[tokbase + grow];
        float* orow = out + (size_t)tokid * D_MODEL + n0;
#pragma unroll
        for (int j = 0; j < 4; ++j) {
          int col = wn * 64 + j * 16 + r16;
          atomicAdd(&orow[col], gate * (acc[i][j][jj] + b2v[j]));
        }
      }
    }
  }
}

extern "C" void kernel_launch(void* const* d_in, const int* in_sizes, int n_in,
                              void* d_out, int out_size, void* d_ws, size_t ws_size,
                              hipStream_t stream) {
  const float* x  = (const float*)d_in[0];
  const float* rw = (const float*)d_in[1];
  const float* rb = (const float*)d_in[2];
  const float* w1 = (const float*)d_in[3];
  const float* b1 = (const float*)d_in[4];
  const float* w2 = (const float*)d_in[5];
  const float* b2 = (const float*)d_in[6];
  float* out = (float*)d_out;
  char* ws = (char*)d_ws;

  int*   cnt = (int*)ws;
  int*   tok = (int*)(ws + 256);
  float* gat = (float*)(ws + 256 + (size_t)NE * T_TOK * 4);

  size_t off = HOFF;
  unsigned short* xb  = (unsigned short*)(ws + off); off += (size_t)T_TOK * D_MODEL * 2;
  unsigned short* w1t = (unsigned short*)(ws + off); off += (size_t)NE * D_MODEL * D_FF * 2;
  unsigned short* w2t = (unsigned short*)(ws + off); off += (size_t)NE * D_MODEL * D_FF * 2;
  unsigned short* H   = (unsigned short*)(ws + off);

  // choose number of d_ff chunks so H (34816 padded rows x FC bf16) fits ws
  int nch = 1;
  while (nch < 16 && off + 34816ull * (size_t)(D_FF / nch) * 2ull > ws_size) nch <<= 1;
  int FC = D_FF / nch;

  hipMemsetAsync(cnt, 0, 64, stream);
  hipMemsetAsync(out, 0, (size_t)out_size * 4, stream);
  cvt_x_kernel<<<dim3(T_TOK * D_MODEL / 2048), dim3(256), 0, stream>>>(x, xb);
  transpose_cvt_kernel<<<dim3(D_FF / 64, D_MODEL / 64, NE), dim3(256), 0, stream>>>(w1, w1t, D_MODEL, D_FF);
  transpose_cvt_kernel<<<dim3(D_MODEL / 64, D_FF / 64, NE), dim3(256), 0, stream>>>(w2, w2t, D_FF, D_MODEL);
  router_kernel<<<dim3(T_TOK / 4), dim3(256), 0, stream>>>(x, rw, rb, cnt, tok, gat);
  for (int ch = 0; ch < nch; ++ch) {
    gemm1_kernel<<<dim3(MAXT, FC / 256), dim3(512), 0, stream>>>(xb, w1t, b1, cnt, tok, H, ch, FC);
    gemm2_kernel<<<dim3(MAXT, D_MODEL / 256), dim3(512), 0, stream>>>(H, w2t, b2, cnt, tok, gat, out, ch, FC);
  }
}

// Round 4
// 1279.386 us; speedup vs baseline: 1.7304x; 1.0773x over previous
//
#include <hip/hip_runtime.h>

#define D_MODEL 1024
#define D_FF    4096
#define NE      8
#define T_TOK   16384
#define MAXT    136
#define HOFF    (2u * 1024u * 1024u)

using frag_ab = __attribute__((ext_vector_type(8))) short;
using f32x4   = __attribute__((ext_vector_type(4))) float;
using ushort8 = __attribute__((ext_vector_type(8))) unsigned short;
using ushort4v = __attribute__((ext_vector_type(4))) unsigned short;

__device__ __forceinline__ unsigned short f2bf(float f) {
  unsigned int u = __builtin_bit_cast(unsigned int, f);
  u += 0x7FFFu + ((u >> 16) & 1u);   // round-to-nearest-even
  return (unsigned short)(u >> 16);
}
__device__ __forceinline__ float bf2f(unsigned short s) {
  unsigned int u = ((unsigned int)s) << 16;
  return __builtin_bit_cast(float, u);
}

__device__ __forceinline__ float gelu_f(float v) {
  return 0.5f * v * (1.0f + erff(v * 0.70710678118654752f));
}

__device__ __forceinline__ void gload16(const void* g, void* l) {
  __builtin_amdgcn_global_load_lds((const __attribute__((address_space(1))) void*)g,
                                   (__attribute__((address_space(3))) void*)l, 16, 0, 0);
}

#define FENCE __builtin_amdgcn_sched_barrier(0)
#define BARRIER do { FENCE; __builtin_amdgcn_s_barrier(); FENCE; } while (0)
__device__ __forceinline__ void waitv(int n) {
  if (n == 6) asm volatile("s_waitcnt vmcnt(6)" ::: "memory");
  else        asm volatile("s_waitcnt vmcnt(0)" ::: "memory");
}

// ---------------- Router: 1 wave per token, f64 logits, top-2 + softmax ----
__global__ void router_kernel(const float* __restrict__ x, const float* __restrict__ rw,
                              const float* __restrict__ rb, int* __restrict__ cnt,
                              int* __restrict__ tok, int* __restrict__ mi,
                              float* __restrict__ mg) {
  int gtid = blockIdx.x * blockDim.x + threadIdx.x;
  int t = gtid >> 6;
  int lane = threadIdx.x & 63;
  if (t >= T_TOK) return;
  const float* xr = x + (size_t)t * D_MODEL;
  double acc[NE];
#pragma unroll
  for (int e = 0; e < NE; ++e) acc[e] = 0.0;
  for (int j = lane; j < D_MODEL; j += 64) {
    double xv = (double)xr[j];
    const float* wr = rw + (size_t)j * NE;
#pragma unroll
    for (int e = 0; e < NE; ++e) acc[e] += xv * (double)wr[e];
  }
#pragma unroll
  for (int e = 0; e < NE; ++e) {
    double v = acc[e];
#pragma unroll
    for (int s = 32; s > 0; s >>= 1) v += __shfl_xor(v, s, 64);
    acc[e] = v;
  }
  if (lane == 0) {
    double lg[NE];
#pragma unroll
    for (int e = 0; e < NE; ++e) lg[e] = acc[e] + (double)rb[e];
    int b0 = 0; double v0 = lg[0];
#pragma unroll
    for (int e = 1; e < NE; ++e) if (lg[e] > v0) { v0 = lg[e]; b0 = e; }
    int b1 = -1; double v1 = -1.0e300;
#pragma unroll
    for (int e = 0; e < NE; ++e) if (e != b0 && lg[e] > v1) { v1 = lg[e]; b1 = e; }
    double g0 = 1.0 / (1.0 + exp(v1 - v0));
    int p0 = atomicAdd(&cnt[b0], 1);
    tok[b0 * T_TOK + p0] = t;
    int p1 = atomicAdd(&cnt[b1], 1);
    tok[b1 * T_TOK + p1] = t;
    mi[4 * t + 0] = b0; mi[4 * t + 1] = b1;
    mi[4 * t + 2] = p0; mi[4 * t + 3] = p1;
    mg[2 * t + 0] = (float)g0; mg[2 * t + 1] = (float)(1.0 - g0);
  }
}

// ---------------- Prepass: x f32 -> bf16 ------------------------------------
__global__ __launch_bounds__(256) void cvt_x_kernel(const float* __restrict__ x,
                                                    unsigned short* __restrict__ xb) {
  size_t i = ((size_t)blockIdx.x * 256 + threadIdx.x) * 8;
  float4 v0 = *(const float4*)(x + i);
  float4 v1 = *(const float4*)(x + i + 4);
  ushort8 o;
  o[0] = f2bf(v0.x); o[1] = f2bf(v0.y); o[2] = f2bf(v0.z); o[3] = f2bf(v0.w);
  o[4] = f2bf(v1.x); o[5] = f2bf(v1.y); o[6] = f2bf(v1.z); o[7] = f2bf(v1.w);
  *(ushort8*)(xb + i) = o;
}

// ---------------- Prepass: transpose+convert [E][R][C] f32 -> [E][C][R] bf16
__global__ __launch_bounds__(256) void transpose_cvt_kernel(const float* __restrict__ in,
                                                            unsigned short* __restrict__ out,
                                                            int R, int C) {
  __shared__ unsigned short tile[64][66];
  int e = blockIdx.z;
  int r0 = blockIdx.y * 64, c0 = blockIdx.x * 64;
  int t = threadIdx.x;
  int rr = t >> 4, cc = (t & 15) * 4;
  const float* src = in + ((size_t)e * R + r0) * C + c0;
#pragma unroll
  for (int p = 0; p < 4; ++p) {
    int r = rr + p * 16;
    float4 v = *(const float4*)(src + (size_t)r * C + cc);
    tile[r][cc + 0] = f2bf(v.x);
    tile[r][cc + 1] = f2bf(v.y);
    tile[r][cc + 2] = f2bf(v.z);
    tile[r][cc + 3] = f2bf(v.w);
  }
  __syncthreads();
  int oc = t >> 2, kc = (t & 3) * 16;
  ushort8 v0, v1;
#pragma unroll
  for (int i = 0; i < 8; ++i) v0[i] = tile[kc + i][oc];
#pragma unroll
  for (int i = 0; i < 8; ++i) v1[i] = tile[kc + 8 + i][oc];
  unsigned short* dst = out + ((size_t)e * C + c0 + oc) * R + r0 + kc;
  *(ushort8*)dst = v0;
  *(ushort8*)(dst + 8) = v1;
}

// map 256-row tile slot -> (expert, local tile, n_e, padded H base row)
__device__ __forceinline__ int find_tile256(const int* __restrict__ cnt, int slot,
                                            int& e, int& lt, int& ne, int& hb) {
  int tacc = 0, base = 0;
  for (int i = 0; i < NE; ++i) {
    int n = cnt[i];
    int tl = (n + 255) >> 8;
    if (slot < tacc + tl) { e = i; lt = slot - tacc; ne = n; hb = base; return 1; }
    tacc += tl; base += tl << 8;
  }
  return 0;
}

// ===================== 256x256x64 8-phase GEMM body =========================
#define STG_A(qa, kt, b) do { \
    gload16(pA##qa##0 + (size_t)(kt) * 64, ldsp + (b) * 65536 + dA + (qa) * 8192); \
    gload16(pA##qa##1 + (size_t)(kt) * 64, ldsp + (b) * 65536 + dA + (qa) * 8192 + 16384); \
  } while (0)
#define STG_B(qb, kt, b) do { \
    gload16(pB##qb##0 + (size_t)(kt) * 64, ldsp + (b) * 65536 + 32768 + dB + (qb) * 4096); \
    gload16(pB##qb##1 + (size_t)(kt) * 64, ldsp + (b) * 65536 + 32768 + dB + (qb) * 4096 + 16384); \
  } while (0)

#define GEMM_BODY(NTILES)                                                        \
  f32x4 acc[8][4] = {};                                                          \
  frag_ab a[4][2], bb[4][2];                                                     \
  const int NT = (NTILES);                                                       \
  STG_A(0, 0, 0); STG_B(0, 0, 0); STG_B(1, 0, 0); STG_A(1, 0, 0);                \
  STG_A(0, 1, 1); STG_B(0, 1, 1); STG_B(1, 1, 1);                                \
  waitv(6); BARRIER;                                                             \
  for (int t = 0; t < NT; ++t) {                                                 \
    const char* AB = ldsp + (t & 1) * 65536;                                     \
    _Pragma("unroll") for (int i = 0; i < 4; ++i) {                              \
      a[i][0] = *(const frag_ab*)(AB + aoff + i * 2048 + xs0);                   \
      a[i][1] = *(const frag_ab*)(AB + aoff + i * 2048 + xs1);                   \
    }                                                                            \
    _Pragma("unroll") for (int j = 0; j < 2; ++j) {                              \
      bb[j][0] = *(const frag_ab*)(AB + boff + j * 2048 + xs0);                  \
      bb[j][1] = *(const frag_ab*)(AB + boff + j * 2048 + xs1);                  \
    }                                                                            \
    if (t + 1 < NT) STG_A(1, t + 1, (t + 1) & 1);                                \
    BARRIER;                                                                     \
    __builtin_amdgcn_s_setprio(1);                                               \
    _Pragma("unroll") for (int i = 0; i < 4; ++i)                                \
      _Pragma("unroll") for (int j = 0; j < 2; ++j) {                            \
        acc[i][j] = __builtin_amdgcn_mfma_f32_16x16x32_bf16(a[i][0], bb[j][0], acc[i][j], 0, 0, 0); \
        acc[i][j] = __builtin_amdgcn_mfma_f32_16x16x32_bf16(a[i][1], bb[j][1], acc[i][j], 0, 0, 0); \
      }                                                                          \
    __builtin_amdgcn_s_setprio(0);                                               \
    BARRIER;                                                                     \
    _Pragma("unroll") for (int j = 0; j < 2; ++j) {                              \
      bb[2 + j][0] = *(const frag_ab*)(AB + boff + (2 + j) * 2048 + xs0);        \
      bb[2 + j][1] = *(const frag_ab*)(AB + boff + (2 + j) * 2048 + xs1);        \
    }                                                                            \
    if (t + 2 < NT) STG_A(0, t + 2, t & 1);                                      \
    BARRIER;                                                                     \
    __builtin_amdgcn_s_setprio(1);                                               \
    _Pragma("unroll") for (int i = 0; i < 4; ++i)                                \
      _Pragma("unroll") for (int j = 0; j < 2; ++j) {                            \
        acc[i][2 + j] = __builtin_amdgcn_mfma_f32_16x16x32_bf16(a[i][0], bb[2 + j][0], acc[i][2 + j], 0, 0, 0); \
        acc[i][2 + j] = __builtin_amdgcn_mfma_f32_16x16x32_bf16(a[i][1], bb[2 + j][1], acc[i][2 + j], 0, 0, 0); \
      }                                                                          \
    __builtin_amdgcn_s_setprio(0);                                               \
    BARRIER;                                                                     \
    _Pragma("unroll") for (int i = 0; i < 4; ++i) {                              \
      a[i][0] = *(const frag_ab*)(AB + aoff + 8192 + i * 2048 + xs0);            \
      a[i][1] = *(const frag_ab*)(AB + aoff + 8192 + i * 2048 + xs1);            \
    }                                                                            \
    if (t + 2 < NT) STG_B(0, t + 2, t & 1);                                      \
    BARRIER;                                                                     \
    __builtin_amdgcn_s_setprio(1);                                               \
    _Pragma("unroll") for (int i = 0; i < 4; ++i)                                \
      _Pragma("unroll") for (int j = 0; j < 2; ++j) {                            \
        acc[4 + i][2 + j] = __builtin_amdgcn_mfma_f32_16x16x32_bf16(a[i][0], bb[2 + j][0], acc[4 + i][2 + j], 0, 0, 0); \
        acc[4 + i][2 + j] = __builtin_amdgcn_mfma_f32_16x16x32_bf16(a[i][1], bb[2 + j][1], acc[4 + i][2 + j], 0, 0, 0); \
      }                                                                          \
    __builtin_amdgcn_s_setprio(0);                                               \
    BARRIER;                                                                     \
    if (t + 2 < NT) STG_B(1, t + 2, t & 1);                                      \
    BARRIER;                                                                     \
    __builtin_amdgcn_s_setprio(1);                                               \
    _Pragma("unroll") for (int i = 0; i < 4; ++i)                                \
      _Pragma("unroll") for (int j = 0; j < 2; ++j) {                            \
        acc[4 + i][j] = __builtin_amdgcn_mfma_f32_16x16x32_bf16(a[i][0], bb[j][0], acc[4 + i][j], 0, 0, 0); \
        acc[4 + i][j] = __builtin_amdgcn_mfma_f32_16x16x32_bf16(a[i][1], bb[j][1], acc[4 + i][j], 0, 0, 0); \
      }                                                                          \
    __builtin_amdgcn_s_setprio(0);                                               \
    waitv((t + 2 < NT) ? 6 : 0);                                                 \
    BARRIER;                                                                     \
  }

// ---------------- GEMM1: H = gelu(gather(xb) @ w1t[e]^T + b1[e]) ------------
__global__ __launch_bounds__(512, 2) void gemm1_kernel(
    const unsigned short* __restrict__ xb, const unsigned short* __restrict__ w1t,
    const float* __restrict__ b1, const int* __restrict__ cnt, const int* __restrict__ tok,
    unsigned short* __restrict__ H) {
  __shared__ __align__(16) char lds[131072];
  int e, lt, ne, hb;
  if (!find_tile256(cnt, blockIdx.y, e, lt, ne, hb)) return;
  char* ldsp = (char*)lds;
  const int tid = threadIdx.x;
  const int lane = tid & 63, w = tid >> 6;
  const int wm = w >> 2, wn = w & 3;
  const int r16 = lane & 15, kg = lane >> 4;
  const int n0 = blockIdx.x * 256;

  const int xs0 = (kg ^ (r16 & 7)) * 16;
  const int xs1 = ((4 + kg) ^ (r16 & 7)) * 16;
  const int aoff = (wm * 128 + r16) * 128;
  const int boff = 32768 + (wn * 64 + r16) * 128;

  const int v = w * 8 + (lane >> 3);
  const int c8off = ((lane & 7) ^ ((lane >> 3) & 7)) * 8;
  const int dA = w * 1024;
  const int dB = (w & 3) * 1024 + (w >> 2) * 8192;
  const int tokbase = e * T_TOK;
  int rA00 = v, rA01 = v + 128, rA10 = 64 + v, rA11 = 192 + v;
  int g00 = lt * 256 + rA00, g01 = lt * 256 + rA01, g10 = lt * 256 + rA10, g11 = lt * 256 + rA11;
  int tk00 = tok[tokbase + ((g00 < ne) ? g00 : 0)];
  int tk01 = tok[tokbase + ((g01 < ne) ? g01 : 0)];
  int tk10 = tok[tokbase + ((g10 < ne) ? g10 : 0)];
  int tk11 = tok[tokbase + ((g11 < ne) ? g11 : 0)];
  const unsigned short* pA00 = xb + (size_t)tk00 * D_MODEL + c8off;
  const unsigned short* pA01 = xb + (size_t)tk01 * D_MODEL + c8off;
  const unsigned short* pA10 = xb + (size_t)tk10 * D_MODEL + c8off;
  const unsigned short* pA11 = xb + (size_t)tk11 * D_MODEL + c8off;
  int rB00 = (v & 31) + (v >> 5) * 64;
  int rB01 = rB00 + 128, rB10 = rB00 + 32, rB11 = rB00 + 160;
  const unsigned short* pB00 = w1t + ((size_t)e * D_FF + n0 + rB00) * D_MODEL + c8off;
  const unsigned short* pB01 = w1t + ((size_t)e * D_FF + n0 + rB01) * D_MODEL + c8off;
  const unsigned short* pB10 = w1t + ((size_t)e * D_FF + n0 + rB10) * D_MODEL + c8off;
  const unsigned short* pB11 = w1t + ((size_t)e * D_FF + n0 + rB11) * D_MODEL + c8off;

  GEMM_BODY(D_MODEL / 64)

  // epilogue: bias + gelu -> bf16, LDS transpose (chunk-XOR), nt vector stores
  unsigned short (*hlds)[272] = (unsigned short (*)[272])ldsp;
  float b1v[4];
#pragma unroll
  for (int j = 0; j < 4; ++j)
    b1v[j] = b1[e * D_FF + n0 + wn * 64 + j * 16 + r16];
#pragma unroll
  for (int ih = 0; ih < 2; ++ih) {
    if (ih) BARRIER;
#pragma unroll
    for (int i2 = 0; i2 < 4; ++i2)
#pragma unroll
      for (int jj = 0; jj < 4; ++jj) {
        int rl = wm * 64 + i2 * 16 + kg * 4 + jj;
#pragma unroll
        for (int j = 0; j < 4; ++j) {
          int col = wn * 64 + j * 16 + r16;
          int pos = (((col >> 3) ^ (rl & 7)) << 3) | (col & 7);
          hlds[rl][pos] = f2bf(gelu_f(acc[ih * 4 + i2][j][jj] + b1v[j]));
        }
      }
    BARRIER;
    int lrow = tid >> 2, cq = tid & 3;
    int grow = (lrow >> 6) * 128 + ih * 64 + (lrow & 63);
    unsigned short* hdst = H + (size_t)(hb + lt * 256 + grow) * D_FF + n0 + cq * 8;
#pragma unroll
    for (int c = 0; c < 8; ++c) {
      int k = cq + c * 4;
      ushort8 vv = *(const ushort8*)&hlds[lrow][(k ^ (lrow & 7)) << 3];
      __builtin_nontemporal_store(vv, (ushort8*)(hdst + c * 32));
    }
  }
}

// ---------------- GEMM2: Y = H @ w2t[e]^T + b2[e], bf16, no atomics ---------
__global__ __launch_bounds__(512, 2) void gemm2_kernel(
    const unsigned short* __restrict__ H, const unsigned short* __restrict__ w2t,
    const float* __restrict__ b2, const int* __restrict__ cnt,
    unsigned short* __restrict__ Y) {
  __shared__ __align__(16) char lds[131072];
  int e, lt, ne, hb;
  if (!find_tile256(cnt, blockIdx.y, e, lt, ne, hb)) return;
  char* ldsp = (char*)lds;
  const int tid = threadIdx.x;
  const int lane = tid & 63, w = tid >> 6;
  const int wm = w >> 2, wn = w & 3;
  const int r16 = lane & 15, kg = lane >> 4;
  const int n0 = blockIdx.x * 256;

  const int xs0 = (kg ^ (r16 & 7)) * 16;
  const int xs1 = ((4 + kg) ^ (r16 & 7)) * 16;
  const int aoff = (wm * 128 + r16) * 128;
  const int boff = 32768 + (wn * 64 + r16) * 128;

  const int v = w * 8 + (lane >> 3);
  const int c8off = ((lane & 7) ^ ((lane >> 3) & 7)) * 8;
  const int dA = w * 1024;
  const int dB = (w & 3) * 1024 + (w >> 2) * 8192;
  int rA00 = v, rA01 = v + 128, rA10 = 64 + v, rA11 = 192 + v;
  const unsigned short* pA00 = H + (size_t)(hb + lt * 256 + rA00) * D_FF + c8off;
  const unsigned short* pA01 = H + (size_t)(hb + lt * 256 + rA01) * D_FF + c8off;
  const unsigned short* pA10 = H + (size_t)(hb + lt * 256 + rA10) * D_FF + c8off;
  const unsigned short* pA11 = H + (size_t)(hb + lt * 256 + rA11) * D_FF + c8off;
  int rB00 = (v & 31) + (v >> 5) * 64;
  int rB01 = rB00 + 128, rB10 = rB00 + 32, rB11 = rB00 + 160;
  const unsigned short* pB00 = w2t + ((size_t)e * D_MODEL + n0 + rB00) * D_FF + c8off;
  const unsigned short* pB01 = w2t + ((size_t)e * D_MODEL + n0 + rB01) * D_FF + c8off;
  const unsigned short* pB10 = w2t + ((size_t)e * D_MODEL + n0 + rB10) * D_FF + c8off;
  const unsigned short* pB11 = w2t + ((size_t)e * D_MODEL + n0 + rB11) * D_FF + c8off;

  GEMM_BODY(D_FF / 64)

  // epilogue: bias -> bf16 Y, LDS transpose, nt vector stores (no mask:
  // junk padded rows are never read by combine)
  unsigned short (*hlds)[272] = (unsigned short (*)[272])ldsp;
  float b2v[4];
#pragma unroll
  for (int j = 0; j < 4; ++j)
    b2v[j] = b2[e * D_MODEL + n0 + wn * 64 + j * 16 + r16];
#pragma unroll
  for (int ih = 0; ih < 2; ++ih) {
    if (ih) BARRIER;
#pragma unroll
    for (int i2 = 0; i2 < 4; ++i2)
#pragma unroll
      for (int jj = 0; jj < 4; ++jj) {
        int rl = wm * 64 + i2 * 16 + kg * 4 + jj;
#pragma unroll
        for (int j = 0; j < 4; ++j) {
          int col = wn * 64 + j * 16 + r16;
          int pos = (((col >> 3) ^ (rl & 7)) << 3) | (col & 7);
          hlds[rl][pos] = f2bf(acc[ih * 4 + i2][j][jj] + b2v[j]);
        }
      }
    BARRIER;
    int lrow = tid >> 2, cq = tid & 3;
    int grow = (lrow >> 6) * 128 + ih * 64 + (lrow & 63);
    unsigned short* ydst = Y + (size_t)(hb + lt * 256 + grow) * D_MODEL + n0 + cq * 8;
#pragma unroll
    for (int c = 0; c < 8; ++c) {
      int k = cq + c * 4;
      ushort8 vv = *(const ushort8*)&hlds[lrow][(k ^ (lrow & 7)) << 3];
      __builtin_nontemporal_store(vv, (ushort8*)(ydst + c * 32));
    }
  }
}

// ---------------- Combine: out[t] = g0*Y[slot0] + g1*Y[slot1] ---------------
__global__ __launch_bounds__(256) void combine_kernel(
    const unsigned short* __restrict__ Y, const int* __restrict__ cnt,
    const int* __restrict__ mi, const float* __restrict__ mg,
    float* __restrict__ out) {
  int w = threadIdx.x >> 6, lane = threadIdx.x & 63;
  int t = blockIdx.x * 4 + w;
  int e0 = mi[4 * t], e1 = mi[4 * t + 1], p0 = mi[4 * t + 2], p1 = mi[4 * t + 3];
  float g0 = mg[2 * t], g1 = mg[2 * t + 1];
  int hbA = 0, hbB = 0, accv = 0;
#pragma unroll
  for (int e = 0; e < NE; ++e) {
    if (e == e0) hbA = accv;
    if (e == e1) hbB = accv;
    accv += (cnt[e] + 255) & ~255;
  }
  const unsigned short* ra = Y + (size_t)(hbA + p0) * D_MODEL;
  const unsigned short* rb = Y + (size_t)(hbB + p1) * D_MODEL;
  float* orow = out + (size_t)t * D_MODEL;
#pragma unroll
  for (int it = 0; it < 4; ++it) {
    int c = it * 256 + lane * 4;
    ushort4v va = *(const ushort4v*)(ra + c);
    ushort4v vb = *(const ushort4v*)(rb + c);
    f32x4 o;
#pragma unroll
    for (int k = 0; k < 4; ++k) o[k] = g0 * bf2f(va[k]) + g1 * bf2f(vb[k]);
    *(f32x4*)(orow + c) = o;
  }
}

extern "C" void kernel_launch(void* const* d_in, const int* in_sizes, int n_in,
                              void* d_out, int out_size, void* d_ws, size_t ws_size,
                              hipStream_t stream) {
  const float* x  = (const float*)d_in[0];
  const float* rw = (const float*)d_in[1];
  const float* rb = (const float*)d_in[2];
  const float* w1 = (const float*)d_in[3];
  const float* b1 = (const float*)d_in[4];
  const float* w2 = (const float*)d_in[5];
  const float* b2 = (const float*)d_in[6];
  float* out = (float*)d_out;
  char* ws = (char*)d_ws;

  int*   cnt = (int*)ws;                                   // 256 B
  int*   tok = (int*)(ws + 256);                           // 512 KB
  int*   mi  = (int*)(ws + 256 + 524288);                  // 256 KB
  float* mg  = (float*)(ws + 256 + 524288 + 262144);       // 128 KB

  // big buffers (fixed layout; round-3 proved ws >= ~455 MB):
  //   xb  @HOFF                33.5 MB   (dead after gemm1)
  //   w1t @+33.5 MB            64   MB   (dead after gemm1)
  //   w2t @+97.5 MB            64   MB
  //   H   @+161.5 MB           285  MB
  //   Y   @HOFF (overlaps xb/w1t: 71.3 MB <= 97.5 MB, written by gemm2)
  unsigned short* xb  = (unsigned short*)(ws + HOFF);
  unsigned short* w1t = (unsigned short*)(ws + HOFF + 33554432u);
  unsigned short* w2t = (unsigned short*)(ws + HOFF + 33554432u + 67108864u);
  unsigned short* H   = (unsigned short*)(ws + HOFF + 33554432u + 67108864u + 67108864u);
  unsigned short* Y   = (unsigned short*)(ws + HOFF);

  hipMemsetAsync(cnt, 0, 64, stream);
  cvt_x_kernel<<<dim3(T_TOK * D_MODEL / 2048), dim3(256), 0, stream>>>(x, xb);
  transpose_cvt_kernel<<<dim3(D_FF / 64, D_MODEL / 64, NE), dim3(256), 0, stream>>>(w1, w1t, D_MODEL, D_FF);
  transpose_cvt_kernel<<<dim3(D_MODEL / 64, D_FF / 64, NE), dim3(256), 0, stream>>>(w2, w2t, D_FF, D_MODEL);
  router_kernel<<<dim3(T_TOK / 4), dim3(256), 0, stream>>>(x, rw, rb, cnt, tok, mi, mg);
  gemm1_kernel<<<dim3(D_FF / 256, MAXT), dim3(512), 0, stream>>>(xb, w1t, b1, cnt, tok, H);
  gemm2_kernel<<<dim3(D_MODEL / 256, MAXT), dim3(512), 0, stream>>>(H, w2t, b2, cnt, Y);
  combine_kernel<<<dim3(T_TOK / 4), dim3(256), 0, stream>>>(Y, cnt, mi, mg, out);
}

// Round 5
// 1175.074 us; speedup vs baseline: 1.8840x; 1.0888x over previous
//
#include <hip/hip_runtime.h>

#define D_MODEL 1024
#define D_FF    4096
#define NE      8
#define T_TOK   16384
#define HOFF    (2u * 1024u * 1024u)

using frag_ab = __attribute__((ext_vector_type(8))) short;
using f32x4   = __attribute__((ext_vector_type(4))) float;
using ushort8 = __attribute__((ext_vector_type(8))) unsigned short;
using ushort4v = __attribute__((ext_vector_type(4))) unsigned short;

__device__ __forceinline__ unsigned short f2bf(float f) {
  unsigned int u = __builtin_bit_cast(unsigned int, f);
  u += 0x7FFFu + ((u >> 16) & 1u);   // round-to-nearest-even
  return (unsigned short)(u >> 16);
}
__device__ __forceinline__ float bf2f(unsigned short s) {
  unsigned int u = ((unsigned int)s) << 16;
  return __builtin_bit_cast(float, u);
}

// fast exact-erf GELU: A&S 7.1.26, |err_erf| <= 1.5e-7 (<< bf16 rounding)
__device__ __forceinline__ float gelu_f(float v) {
  float z  = v * 0.70710678118654752f;
  float az = __builtin_fabsf(z);
  float d  = __builtin_fmaf(0.3275911f, az, 1.0f);
  float t;
  asm("v_rcp_f32_e32 %0, %1" : "=v"(t) : "v"(d));
  t = t * (2.0f - d * t);                       // one NR refine
  float p = __builtin_fmaf(t, 1.061405429f, -1.453152027f);
  p = __builtin_fmaf(t, p, 1.421413741f);
  p = __builtin_fmaf(t, p, -0.284496736f);
  p = __builtin_fmaf(t, p, 0.254829592f);
  p = p * t;
  float ex = __expf(-az * az);
  float er = __builtin_fmaf(-p, ex, 1.0f);      // erf(|z|)
  unsigned int su = __builtin_bit_cast(unsigned int, z) & 0x80000000u;
  er = __builtin_bit_cast(float, __builtin_bit_cast(unsigned int, er) | su);
  return 0.5f * v * (1.0f + er);
}

__device__ __forceinline__ void gload16(const void* g, void* l) {
  __builtin_amdgcn_global_load_lds((const __attribute__((address_space(1))) void*)g,
                                   (__attribute__((address_space(3))) void*)l, 16, 0, 0);
}

#define FENCE __builtin_amdgcn_sched_barrier(0)
#define BARRIER do { FENCE; __builtin_amdgcn_s_barrier(); FENCE; } while (0)
__device__ __forceinline__ void waitv(int n) {
  if (n == 6) asm volatile("s_waitcnt vmcnt(6)" ::: "memory");
  else        asm volatile("s_waitcnt vmcnt(0)" ::: "memory");
}

// ------- Router (+ fused x->bf16 convert): 1 wave/token, f64 top-2 ---------
__global__ __launch_bounds__(256) void router_kernel(
    const float* __restrict__ x, const float* __restrict__ rw,
    const float* __restrict__ rb, int* __restrict__ cnt,
    int* __restrict__ tok, int* __restrict__ mi, float* __restrict__ mg,
    unsigned short* __restrict__ xb) {
  int t = blockIdx.x * 4 + (threadIdx.x >> 6);
  int lane = threadIdx.x & 63;
  if (t >= T_TOK) return;
  const float* xr = x + (size_t)t * D_MODEL;
  unsigned short* xbr = xb + (size_t)t * D_MODEL;
  double acc[NE];
#pragma unroll
  for (int e = 0; e < NE; ++e) acc[e] = 0.0;
#pragma unroll
  for (int it = 0; it < 4; ++it) {
    int j = it * 256 + lane * 4;
    float4 v = *(const float4*)(xr + j);
    ushort4v o;
    o[0] = f2bf(v.x); o[1] = f2bf(v.y); o[2] = f2bf(v.z); o[3] = f2bf(v.w);
    *(ushort4v*)(xbr + j) = o;
    const float* w0 = rw + (size_t)j * NE;
    const float vv[4] = {v.x, v.y, v.z, v.w};
#pragma unroll
    for (int q = 0; q < 4; ++q) {
      double xv = (double)vv[q];
#pragma unroll
      for (int e = 0; e < NE; ++e) acc[e] += xv * (double)w0[q * NE + e];
    }
  }
#pragma unroll
  for (int e = 0; e < NE; ++e) {
    double v = acc[e];
#pragma unroll
    for (int s = 32; s > 0; s >>= 1) v += __shfl_xor(v, s, 64);
    acc[e] = v;
  }
  if (lane == 0) {
    double lg[NE];
#pragma unroll
    for (int e = 0; e < NE; ++e) lg[e] = acc[e] + (double)rb[e];
    int b0 = 0; double v0 = lg[0];
#pragma unroll
    for (int e = 1; e < NE; ++e) if (lg[e] > v0) { v0 = lg[e]; b0 = e; }
    int b1 = -1; double v1 = -1.0e300;
#pragma unroll
    for (int e = 0; e < NE; ++e) if (e != b0 && lg[e] > v1) { v1 = lg[e]; b1 = e; }
    double g0 = 1.0 / (1.0 + exp(v1 - v0));
    int p0 = atomicAdd(&cnt[b0], 1);
    tok[b0 * T_TOK + p0] = t;
    int p1 = atomicAdd(&cnt[b1], 1);
    tok[b1 * T_TOK + p1] = t;
    mi[4 * t + 0] = b0; mi[4 * t + 1] = b1;
    mi[4 * t + 2] = p0; mi[4 * t + 3] = p1;
    mg[2 * t + 0] = (float)g0; mg[2 * t + 1] = (float)(1.0 - g0);
  }
}

// ---------------- Prepass: transpose+convert [E][R][C] f32 -> [E][C][R] bf16
__global__ __launch_bounds__(256) void transpose_cvt_kernel(const float* __restrict__ in,
                                                            unsigned short* __restrict__ out,
                                                            int R, int C) {
  __shared__ unsigned short tile[64][66];
  int e = blockIdx.z;
  int r0 = blockIdx.y * 64, c0 = blockIdx.x * 64;
  int t = threadIdx.x;
  int rr = t >> 4, cc = (t & 15) * 4;
  const float* src = in + ((size_t)e * R + r0) * C + c0;
#pragma unroll
  for (int p = 0; p < 4; ++p) {
    int r = rr + p * 16;
    float4 v = *(const float4*)(src + (size_t)r * C + cc);
    tile[r][cc + 0] = f2bf(v.x);
    tile[r][cc + 1] = f2bf(v.y);
    tile[r][cc + 2] = f2bf(v.z);
    tile[r][cc + 3] = f2bf(v.w);
  }
  __syncthreads();
  int oc = t >> 2, kc = (t & 3) * 16;
  ushort8 v0, v1;
#pragma unroll
  for (int i = 0; i < 8; ++i) v0[i] = tile[kc + i][oc];
#pragma unroll
  for (int i = 0; i < 8; ++i) v1[i] = tile[kc + 8 + i][oc];
  unsigned short* dst = out + ((size_t)e * C + c0 + oc) * R + r0 + kc;
  *(ushort8*)dst = v0;
  *(ushort8*)(dst + 8) = v1;
}

// map 256-row tile slot -> (expert, local tile, n_e, padded H base row)
__device__ __forceinline__ int find_tile256(const int* __restrict__ cnt, int slot,
                                            int& e, int& lt, int& ne, int& hb) {
  int tacc = 0, base = 0;
  for (int i = 0; i < NE; ++i) {
    int n = cnt[i];
    int tl = (n + 255) >> 8;
    if (slot < tacc + tl) { e = i; lt = slot - tacc; ne = n; hb = base; return 1; }
    tacc += tl; base += tl << 8;
  }
  return 0;
}

// ===================== 256x256x64 8-phase GEMM body =========================
#define STG_A(qa, kt, b) do { \
    gload16(pA##qa##0 + (size_t)(kt) * 64, ldsp + (b) * 65536 + dA + (qa) * 8192); \
    gload16(pA##qa##1 + (size_t)(kt) * 64, ldsp + (b) * 65536 + dA + (qa) * 8192 + 16384); \
  } while (0)
#define STG_B(qb, kt, b) do { \
    gload16(pB##qb##0 + (size_t)(kt) * 64, ldsp + (b) * 65536 + 32768 + dB + (qb) * 4096); \
    gload16(pB##qb##1 + (size_t)(kt) * 64, ldsp + (b) * 65536 + 32768 + dB + (qb) * 4096 + 16384); \
  } while (0)

#define GEMM_BODY(NTILES)                                                        \
  f32x4 acc[8][4] = {};                                                          \
  frag_ab a[4][2], bb[4][2];                                                     \
  const int NT = (NTILES);                                                       \
  STG_A(0, 0, 0); STG_B(0, 0, 0); STG_B(1, 0, 0); STG_A(1, 0, 0);                \
  STG_A(0, 1, 1); STG_B(0, 1, 1); STG_B(1, 1, 1);                                \
  waitv(6); BARRIER;                                                             \
  for (int t = 0; t < NT; ++t) {                                                 \
    const char* AB = ldsp + (t & 1) * 65536;                                     \
    _Pragma("unroll") for (int i = 0; i < 4; ++i) {                              \
      a[i][0] = *(const frag_ab*)(AB + aoff + i * 2048 + xs0);                   \
      a[i][1] = *(const frag_ab*)(AB + aoff + i * 2048 + xs1);                   \
    }                                                                            \
    _Pragma("unroll") for (int j = 0; j < 2; ++j) {                              \
      bb[j][0] = *(const frag_ab*)(AB + boff + j * 2048 + xs0);                  \
      bb[j][1] = *(const frag_ab*)(AB + boff + j * 2048 + xs1);                  \
    }                                                                            \
    if (t + 1 < NT) STG_A(1, t + 1, (t + 1) & 1);                                \
    BARRIER;                                                                     \
    __builtin_amdgcn_s_setprio(1);                                               \
    _Pragma("unroll") for (int i = 0; i < 4; ++i)                                \
      _Pragma("unroll") for (int j = 0; j < 2; ++j) {                            \
        acc[i][j] = __builtin_amdgcn_mfma_f32_16x16x32_bf16(a[i][0], bb[j][0], acc[i][j], 0, 0, 0); \
        acc[i][j] = __builtin_amdgcn_mfma_f32_16x16x32_bf16(a[i][1], bb[j][1], acc[i][j], 0, 0, 0); \
      }                                                                          \
    __builtin_amdgcn_s_setprio(0);                                               \
    BARRIER;                                                                     \
    _Pragma("unroll") for (int j = 0; j < 2; ++j) {                              \
      bb[2 + j][0] = *(const frag_ab*)(AB + boff + (2 + j) * 2048 + xs0);        \
      bb[2 + j][1] = *(const frag_ab*)(AB + boff + (2 + j) * 2048 + xs1);        \
    }                                                                            \
    if (t + 2 < NT) STG_A(0, t + 2, t & 1);                                      \
    BARRIER;                                                                     \
    __builtin_amdgcn_s_setprio(1);                                               \
    _Pragma("unroll") for (int i = 0; i < 4; ++i)                                \
      _Pragma("unroll") for (int j = 0; j < 2; ++j) {                            \
        acc[i][2 + j] = __builtin_amdgcn_mfma_f32_16x16x32_bf16(a[i][0], bb[2 + j][0], acc[i][2 + j], 0, 0, 0); \
        acc[i][2 + j] = __builtin_amdgcn_mfma_f32_16x16x32_bf16(a[i][1], bb[2 + j][1], acc[i][2 + j], 0, 0, 0); \
      }                                                                          \
    __builtin_amdgcn_s_setprio(0);                                               \
    BARRIER;                                                                     \
    _Pragma("unroll") for (int i = 0; i < 4; ++i) {                              \
      a[i][0] = *(const frag_ab*)(AB + aoff + 8192 + i * 2048 + xs0);            \
      a[i][1] = *(const frag_ab*)(AB + aoff + 8192 + i * 2048 + xs1);            \
    }                                                                            \
    if (t + 2 < NT) STG_B(0, t + 2, t & 1);                                      \
    BARRIER;                                                                     \
    __builtin_amdgcn_s_setprio(1);                                               \
    _Pragma("unroll") for (int i = 0; i < 4; ++i)                                \
      _Pragma("unroll") for (int j = 0; j < 2; ++j) {                            \
        acc[4 + i][2 + j] = __builtin_amdgcn_mfma_f32_16x16x32_bf16(a[i][0], bb[2 + j][0], acc[4 + i][2 + j], 0, 0, 0); \
        acc[4 + i][2 + j] = __builtin_amdgcn_mfma_f32_16x16x32_bf16(a[i][1], bb[2 + j][1], acc[4 + i][2 + j], 0, 0, 0); \
      }                                                                          \
    __builtin_amdgcn_s_setprio(0);                                               \
    BARRIER;                                                                     \
    if (t + 2 < NT) STG_B(1, t + 2, t & 1);                                      \
    BARRIER;                                                                     \
    __builtin_amdgcn_s_setprio(1);                                               \
    _Pragma("unroll") for (int i = 0; i < 4; ++i)                                \
      _Pragma("unroll") for (int j = 0; j < 2; ++j) {                            \
        acc[4 + i][j] = __builtin_amdgcn_mfma_f32_16x16x32_bf16(a[i][0], bb[j][0], acc[4 + i][j], 0, 0, 0); \
        acc[4 + i][j] = __builtin_amdgcn_mfma_f32_16x16x32_bf16(a[i][1], bb[j][1], acc[4 + i][j], 0, 0, 0); \
      }                                                                          \
    __builtin_amdgcn_s_setprio(0);                                               \
    waitv((t + 2 < NT) ? 6 : 0);                                                 \
    BARRIER;                                                                     \
  }

// ---------------- GEMM1: H = gelu(gather(xb) @ w1t[e]^T + b1[e]) ------------
// XCD-grouped mapping: xcd = bid&7; token-tile tt = xcd + 8*(slot>>4),
// n-tile = slot&15 -> all 16 n-tiles of a tt on ONE XCD (A panel L2-shared).
__global__ __launch_bounds__(512, 2) void gemm1_kernel(
    const unsigned short* __restrict__ xb, const unsigned short* __restrict__ w1t,
    const float* __restrict__ b1, const int* __restrict__ cnt, const int* __restrict__ tok,
    unsigned short* __restrict__ H) {
  __shared__ __align__(16) char lds[131072];
  int bid = blockIdx.x;
  int s = bid >> 3;
  int tt = (bid & 7) + 8 * (s >> 4);
  int e, lt, ne, hb;
  if (!find_tile256(cnt, tt, e, lt, ne, hb)) return;
  char* ldsp = (char*)lds;
  const int tid = threadIdx.x;
  const int lane = tid & 63, w = tid >> 6;
  const int wm = w >> 2, wn = w & 3;
  const int r16 = lane & 15, kg = lane >> 4;
  const int n0 = (s & 15) * 256;

  const int xs0 = (kg ^ (r16 & 7)) * 16;
  const int xs1 = ((4 + kg) ^ (r16 & 7)) * 16;
  const int aoff = (wm * 128 + r16) * 128;
  const int boff = 32768 + (wn * 64 + r16) * 128;

  const int v = w * 8 + (lane >> 3);
  const int c8off = ((lane & 7) ^ ((lane >> 3) & 7)) * 8;
  const int dA = w * 1024;
  const int dB = (w & 3) * 1024 + (w >> 2) * 8192;
  const int tokbase = e * T_TOK;
  int rA00 = v, rA01 = v + 128, rA10 = 64 + v, rA11 = 192 + v;
  int g00 = lt * 256 + rA00, g01 = lt * 256 + rA01, g10 = lt * 256 + rA10, g11 = lt * 256 + rA11;
  int tk00 = tok[tokbase + ((g00 < ne) ? g00 : 0)];
  int tk01 = tok[tokbase + ((g01 < ne) ? g01 : 0)];
  int tk10 = tok[tokbase + ((g10 < ne) ? g10 : 0)];
  int tk11 = tok[tokbase + ((g11 < ne) ? g11 : 0)];
  const unsigned short* pA00 = xb + (size_t)tk00 * D_MODEL + c8off;
  const unsigned short* pA01 = xb + (size_t)tk01 * D_MODEL + c8off;
  const unsigned short* pA10 = xb + (size_t)tk10 * D_MODEL + c8off;
  const unsigned short* pA11 = xb + (size_t)tk11 * D_MODEL + c8off;
  int rB00 = (v & 31) + (v >> 5) * 64;
  int rB01 = rB00 + 128, rB10 = rB00 + 32, rB11 = rB00 + 160;
  const unsigned short* pB00 = w1t + ((size_t)e * D_FF + n0 + rB00) * D_MODEL + c8off;
  const unsigned short* pB01 = w1t + ((size_t)e * D_FF + n0 + rB01) * D_MODEL + c8off;
  const unsigned short* pB10 = w1t + ((size_t)e * D_FF + n0 + rB10) * D_MODEL + c8off;
  const unsigned short* pB11 = w1t + ((size_t)e * D_FF + n0 + rB11) * D_MODEL + c8off;

  GEMM_BODY(D_MODEL / 64)

  // epilogue: bias + gelu -> bf16, LDS transpose (chunk-XOR), nt vector stores
  unsigned short (*hlds)[272] = (unsigned short (*)[272])ldsp;
  float b1v[4];
#pragma unroll
  for (int j = 0; j < 4; ++j)
    b1v[j] = b1[e * D_FF + n0 + wn * 64 + j * 16 + r16];
#pragma unroll
  for (int ih = 0; ih < 2; ++ih) {
    if (ih) BARRIER;
#pragma unroll
    for (int i2 = 0; i2 < 4; ++i2)
#pragma unroll
      for (int jj = 0; jj < 4; ++jj) {
        int rl = wm * 64 + i2 * 16 + kg * 4 + jj;
#pragma unroll
        for (int j = 0; j < 4; ++j) {
          int col = wn * 64 + j * 16 + r16;
          int pos = (((col >> 3) ^ (rl & 7)) << 3) | (col & 7);
          hlds[rl][pos] = f2bf(gelu_f(acc[ih * 4 + i2][j][jj] + b1v[j]));
        }
      }
    BARRIER;
    int lrow = tid >> 2, cq = tid & 3;
    int grow = (lrow >> 6) * 128 + ih * 64 + (lrow & 63);
    unsigned short* hdst = H + (size_t)(hb + lt * 256 + grow) * D_FF + n0 + cq * 8;
#pragma unroll
    for (int c = 0; c < 8; ++c) {
      int k = cq + c * 4;
      ushort8 vv = *(const ushort8*)&hlds[lrow][(k ^ (lrow & 7)) << 3];
      __builtin_nontemporal_store(vv, (ushort8*)(hdst + c * 32));
    }
  }
}

// ---------------- GEMM2: Y = H @ w2t[e]^T + b2[e], bf16, no atomics ---------
// XCD-grouped: the 4 n-tiles of a token-tile on one XCD -> H panel read once.
__global__ __launch_bounds__(512, 2) void gemm2_kernel(
    const unsigned short* __restrict__ H, const unsigned short* __restrict__ w2t,
    const float* __restrict__ b2, const int* __restrict__ cnt,
    unsigned short* __restrict__ Y) {
  __shared__ __align__(16) char lds[131072];
  int bid = blockIdx.x;
  int s = bid >> 3;
  int tt = (bid & 7) + 8 * (s >> 2);
  int e, lt, ne, hb;
  if (!find_tile256(cnt, tt, e, lt, ne, hb)) return;
  char* ldsp = (char*)lds;
  const int tid = threadIdx.x;
  const int lane = tid & 63, w = tid >> 6;
  const int wm = w >> 2, wn = w & 3;
  const int r16 = lane & 15, kg = lane >> 4;
  const int n0 = (s & 3) * 256;

  const int xs0 = (kg ^ (r16 & 7)) * 16;
  const int xs1 = ((4 + kg) ^ (r16 & 7)) * 16;
  const int aoff = (wm * 128 + r16) * 128;
  const int boff = 32768 + (wn * 64 + r16) * 128;

  const int v = w * 8 + (lane >> 3);
  const int c8off = ((lane & 7) ^ ((lane >> 3) & 7)) * 8;
  const int dA = w * 1024;
  const int dB = (w & 3) * 1024 + (w >> 2) * 8192;
  int rA00 = v, rA01 = v + 128, rA10 = 64 + v, rA11 = 192 + v;
  const unsigned short* pA00 = H + (size_t)(hb + lt * 256 + rA00) * D_FF + c8off;
  const unsigned short* pA01 = H + (size_t)(hb + lt * 256 + rA01) * D_FF + c8off;
  const unsigned short* pA10 = H + (size_t)(hb + lt * 256 + rA10) * D_FF + c8off;
  const unsigned short* pA11 = H + (size_t)(hb + lt * 256 + rA11) * D_FF + c8off;
  int rB00 = (v & 31) + (v >> 5) * 64;
  int rB01 = rB00 + 128, rB10 = rB00 + 32, rB11 = rB00 + 160;
  const unsigned short* pB00 = w2t + ((size_t)e * D_MODEL + n0 + rB00) * D_FF + c8off;
  const unsigned short* pB01 = w2t + ((size_t)e * D_MODEL + n0 + rB01) * D_FF + c8off;
  const unsigned short* pB10 = w2t + ((size_t)e * D_MODEL + n0 + rB10) * D_FF + c8off;
  const unsigned short* pB11 = w2t + ((size_t)e * D_MODEL + n0 + rB11) * D_FF + c8off;

  GEMM_BODY(D_FF / 64)

  // epilogue: bias -> bf16 Y, LDS transpose, nt vector stores
  unsigned short (*hlds)[272] = (unsigned short (*)[272])ldsp;
  float b2v[4];
#pragma unroll
  for (int j = 0; j < 4; ++j)
    b2v[j] = b2[e * D_MODEL + n0 + wn * 64 + j * 16 + r16];
#pragma unroll
  for (int ih = 0; ih < 2; ++ih) {
    if (ih) BARRIER;
#pragma unroll
    for (int i2 = 0; i2 < 4; ++i2)
#pragma unroll
      for (int jj = 0; jj < 4; ++jj) {
        int rl = wm * 64 + i2 * 16 + kg * 4 + jj;
#pragma unroll
        for (int j = 0; j < 4; ++j) {
          int col = wn * 64 + j * 16 + r16;
          int pos = (((col >> 3) ^ (rl & 7)) << 3) | (col & 7);
          hlds[rl][pos] = f2bf(acc[ih * 4 + i2][j][jj] + b2v[j]);
        }
      }
    BARRIER;
    int lrow = tid >> 2, cq = tid & 3;
    int grow = (lrow >> 6) * 128 + ih * 64 + (lrow & 63);
    unsigned short* ydst = Y + (size_t)(hb + lt * 256 + grow) * D_MODEL + n0 + cq * 8;
#pragma unroll
    for (int c = 0; c < 8; ++c) {
      int k = cq + c * 4;
      ushort8 vv = *(const ushort8*)&hlds[lrow][(k ^ (lrow & 7)) << 3];
      __builtin_nontemporal_store(vv, (ushort8*)(ydst + c * 32));
    }
  }
}

// ---------------- Combine: out[t] = g0*Y[slot0] + g1*Y[slot1] ---------------
__global__ __launch_bounds__(256) void combine_kernel(
    const unsigned short* __restrict__ Y, const int* __restrict__ cnt,
    const int* __restrict__ mi, const float* __restrict__ mg,
    float* __restrict__ out) {
  int w = threadIdx.x >> 6, lane = threadIdx.x & 63;
  int t = blockIdx.x * 4 + w;
  int e0 = mi[4 * t], e1 = mi[4 * t + 1], p0 = mi[4 * t + 2], p1 = mi[4 * t + 3];
  float g0 = mg[2 * t], g1 = mg[2 * t + 1];
  int hbA = 0, hbB = 0, accv = 0;
#pragma unroll
  for (int e = 0; e < NE; ++e) {
    if (e == e0) hbA = accv;
    if (e == e1) hbB = accv;
    accv += (cnt[e] + 255) & ~255;
  }
  const unsigned short* ra = Y + (size_t)(hbA + p0) * D_MODEL;
  const unsigned short* rb = Y + (size_t)(hbB + p1) * D_MODEL;
  float* orow = out + (size_t)t * D_MODEL;
#pragma unroll
  for (int it = 0; it < 4; ++it) {
    int c = it * 256 + lane * 4;
    ushort4v va = *(const ushort4v*)(ra + c);
    ushort4v vb = *(const ushort4v*)(rb + c);
    f32x4 o;
#pragma unroll
    for (int k = 0; k < 4; ++k) o[k] = g0 * bf2f(va[k]) + g1 * bf2f(vb[k]);
    *(f32x4*)(orow + c) = o;
  }
}

extern "C" void kernel_launch(void* const* d_in, const int* in_sizes, int n_in,
                              void* d_out, int out_size, void* d_ws, size_t ws_size,
                              hipStream_t stream) {
  const float* x  = (const float*)d_in[0];
  const float* rw = (const float*)d_in[1];
  const float* rb = (const float*)d_in[2];
  const float* w1 = (const float*)d_in[3];
  const float* b1 = (const float*)d_in[4];
  const float* w2 = (const float*)d_in[5];
  const float* b2 = (const float*)d_in[6];
  float* out = (float*)d_out;
  char* ws = (char*)d_ws;

  int*   cnt = (int*)ws;                                   // 256 B
  int*   tok = (int*)(ws + 256);                           // 512 KB
  int*   mi  = (int*)(ws + 256 + 524288);                  // 256 KB
  float* mg  = (float*)(ws + 256 + 524288 + 262144);       // 128 KB

  // big buffers: xb 33.5MB | w1t 64MB | w2t 64MB | H 285MB ; Y overlaps xb/w1t
  unsigned short* xb  = (unsigned short*)(ws + HOFF);
  unsigned short* w1t = (unsigned short*)(ws + HOFF + 33554432u);
  unsigned short* w2t = (unsigned short*)(ws + HOFF + 33554432u + 67108864u);
  unsigned short* H   = (unsigned short*)(ws + HOFF + 33554432u + 67108864u + 67108864u);
  unsigned short* Y   = (unsigned short*)(ws + HOFF);

  hipMemsetAsync(cnt, 0, 64, stream);
  router_kernel<<<dim3(T_TOK / 4), dim3(256), 0, stream>>>(x, rw, rb, cnt, tok, mi, mg, xb);
  transpose_cvt_kernel<<<dim3(D_FF / 64, D_MODEL / 64, NE), dim3(256), 0, stream>>>(w1, w1t, D_MODEL, D_FF);
  transpose_cvt_kernel<<<dim3(D_MODEL / 64, D_FF / 64, NE), dim3(256), 0, stream>>>(w2, w2t, D_FF, D_MODEL);
  // grids: 8 XCD groups x 17 token-tile slots x n-tiles
  gemm1_kernel<<<dim3(8 * 17 * 16), dim3(512), 0, stream>>>(xb, w1t, b1, cnt, tok, H);
  gemm2_kernel<<<dim3(8 * 17 * 4), dim3(512), 0, stream>>>(H, w2t, b2, cnt, Y);
  combine_kernel<<<dim3(T_TOK / 4), dim3(256), 0, stream>>>(Y, cnt, mi, mg, out);
}

// Round 6
// 844.302 us; speedup vs baseline: 2.6221x; 1.3918x over previous
//
#include <hip/hip_runtime.h>

#define D_MODEL 1024
#define D_FF    4096
#define NE      8
#define T_TOK   16384
#define HOFF    (2u * 1024u * 1024u)

using frag_ab = __attribute__((ext_vector_type(8))) short;
using f32x4   = __attribute__((ext_vector_type(4))) float;
using ushort8 = __attribute__((ext_vector_type(8))) unsigned short;
using ushort4v = __attribute__((ext_vector_type(4))) unsigned short;

__device__ __forceinline__ unsigned short f2bf(float f) {
  unsigned int u = __builtin_bit_cast(unsigned int, f);
  u += 0x7FFFu + ((u >> 16) & 1u);   // round-to-nearest-even
  return (unsigned short)(u >> 16);
}
__device__ __forceinline__ float bf2f(unsigned short s) {
  unsigned int u = ((unsigned int)s) << 16;
  return __builtin_bit_cast(float, u);
}

// fast exact-erf GELU: A&S 7.1.26, |err_erf| <= 1.5e-7 (<< bf16 rounding)
__device__ __forceinline__ float gelu_f(float v) {
  float z  = v * 0.70710678118654752f;
  float az = __builtin_fabsf(z);
  float d  = __builtin_fmaf(0.3275911f, az, 1.0f);
  float t;
  asm("v_rcp_f32_e32 %0, %1" : "=v"(t) : "v"(d));
  t = t * (2.0f - d * t);                       // one NR refine
  float p = __builtin_fmaf(t, 1.061405429f, -1.453152027f);
  p = __builtin_fmaf(t, p, 1.421413741f);
  p = __builtin_fmaf(t, p, -0.284496736f);
  p = __builtin_fmaf(t, p, 0.254829592f);
  p = p * t;
  float ex = __expf(-az * az);
  float er = __builtin_fmaf(-p, ex, 1.0f);      // erf(|z|)
  unsigned int su = __builtin_bit_cast(unsigned int, z) & 0x80000000u;
  er = __builtin_bit_cast(float, __builtin_bit_cast(unsigned int, er) | su);
  return 0.5f * v * (1.0f + er);
}

__device__ __forceinline__ void gload16(const void* g, void* l) {
  __builtin_amdgcn_global_load_lds((const __attribute__((address_space(1))) void*)g,
                                   (__attribute__((address_space(3))) void*)l, 16, 0, 0);
}

#define FENCE __builtin_amdgcn_sched_barrier(0)
#define BARRIER do { FENCE; __builtin_amdgcn_s_barrier(); FENCE; } while (0)
__device__ __forceinline__ void waitv(int n) {
  if (n == 6) asm volatile("s_waitcnt vmcnt(6)" ::: "memory");
  else        asm volatile("s_waitcnt vmcnt(0)" ::: "memory");
}

// ------- Router (hierarchical, + fused x->bf16): 256 blocks x 64 tokens ----
// Per-token local rank via LDS atomics; ONE global atomicAdd per expert per
// block (2048 total vs 32768 same-line atomics before).
__global__ __launch_bounds__(256) void router_kernel(
    const float* __restrict__ x, const float* __restrict__ rw,
    const float* __restrict__ rb, int* __restrict__ cnt,
    int* __restrict__ tok, int* __restrict__ mi, float* __restrict__ mg,
    unsigned short* __restrict__ xb) {
  __shared__ int lcnt[NE];
  __shared__ int base[NE];
  __shared__ int lexp[64][2];
  __shared__ int lrank[64][2];
  int w = threadIdx.x >> 6, lane = threadIdx.x & 63;
  if (threadIdx.x < NE) lcnt[threadIdx.x] = 0;
  __syncthreads();

  for (int it = 0; it < 16; ++it) {
    int li = w * 16 + it;
    int t = blockIdx.x * 64 + li;
    const float* xr = x + (size_t)t * D_MODEL;
    unsigned short* xbr = xb + (size_t)t * D_MODEL;
    double acc[NE];
#pragma unroll
    for (int e = 0; e < NE; ++e) acc[e] = 0.0;
#pragma unroll
    for (int it2 = 0; it2 < 4; ++it2) {
      int j = it2 * 256 + lane * 4;
      float4 v = *(const float4*)(xr + j);
      ushort4v o;
      o[0] = f2bf(v.x); o[1] = f2bf(v.y); o[2] = f2bf(v.z); o[3] = f2bf(v.w);
      *(ushort4v*)(xbr + j) = o;
      const float* w0 = rw + (size_t)j * NE;
      const float vv[4] = {v.x, v.y, v.z, v.w};
#pragma unroll
      for (int q = 0; q < 4; ++q) {
        double xv = (double)vv[q];
#pragma unroll
        for (int e = 0; e < NE; ++e) acc[e] += xv * (double)w0[q * NE + e];
      }
    }
#pragma unroll
    for (int e = 0; e < NE; ++e) {
      double v = acc[e];
#pragma unroll
      for (int s = 32; s > 0; s >>= 1) v += __shfl_xor(v, s, 64);
      acc[e] = v;
    }
    if (lane == 0) {
      double lg[NE];
#pragma unroll
      for (int e = 0; e < NE; ++e) lg[e] = acc[e] + (double)rb[e];
      int b0 = 0; double v0 = lg[0];
#pragma unroll
      for (int e = 1; e < NE; ++e) if (lg[e] > v0) { v0 = lg[e]; b0 = e; }
      int b1 = -1; double v1 = -1.0e300;
#pragma unroll
      for (int e = 0; e < NE; ++e) if (e != b0 && lg[e] > v1) { v1 = lg[e]; b1 = e; }
      double g0 = 1.0 / (1.0 + exp(v1 - v0));
      lexp[li][0] = b0; lexp[li][1] = b1;
      lrank[li][0] = atomicAdd(&lcnt[b0], 1);
      lrank[li][1] = atomicAdd(&lcnt[b1], 1);
      mg[2 * t + 0] = (float)g0; mg[2 * t + 1] = (float)(1.0 - g0);
    }
  }
  __syncthreads();
  if (threadIdx.x < NE) base[threadIdx.x] = atomicAdd(&cnt[threadIdx.x], lcnt[threadIdx.x]);
  __syncthreads();
  if (threadIdx.x < 64) {
    int li = threadIdx.x;
    int t = blockIdx.x * 64 + li;
    int e0 = lexp[li][0], e1 = lexp[li][1];
    int p0 = base[e0] + lrank[li][0], p1 = base[e1] + lrank[li][1];
    tok[e0 * T_TOK + p0] = t;
    tok[e1 * T_TOK + p1] = t;
    mi[4 * t + 0] = e0; mi[4 * t + 1] = e1;
    mi[4 * t + 2] = p0; mi[4 * t + 3] = p1;
  }
}

// ---------------- Prepass: transpose+convert [E][R][C] f32 -> [E][C][R] bf16
__global__ __launch_bounds__(256) void transpose_cvt_kernel(const float* __restrict__ in,
                                                            unsigned short* __restrict__ out,
                                                            int R, int C) {
  __shared__ unsigned short tile[64][66];
  int e = blockIdx.z;
  int r0 = blockIdx.y * 64, c0 = blockIdx.x * 64;
  int t = threadIdx.x;
  int rr = t >> 4, cc = (t & 15) * 4;
  const float* src = in + ((size_t)e * R + r0) * C + c0;
#pragma unroll
  for (int p = 0; p < 4; ++p) {
    int r = rr + p * 16;
    float4 v = *(const float4*)(src + (size_t)r * C + cc);
    tile[r][cc + 0] = f2bf(v.x);
    tile[r][cc + 1] = f2bf(v.y);
    tile[r][cc + 2] = f2bf(v.z);
    tile[r][cc + 3] = f2bf(v.w);
  }
  __syncthreads();
  int oc = t >> 2, kc = (t & 3) * 16;
  ushort8 v0, v1;
#pragma unroll
  for (int i = 0; i < 8; ++i) v0[i] = tile[kc + i][oc];
#pragma unroll
  for (int i = 0; i < 8; ++i) v1[i] = tile[kc + 8 + i][oc];
  unsigned short* dst = out + ((size_t)e * C + c0 + oc) * R + r0 + kc;
  *(ushort8*)dst = v0;
  *(ushort8*)(dst + 8) = v1;
}

// map 256-row tile slot -> (expert, local tile, n_e, padded H base row)
__device__ __forceinline__ int find_tile256(const int* __restrict__ cnt, int slot,
                                            int& e, int& lt, int& ne, int& hb) {
  int tacc = 0, base = 0;
  for (int i = 0; i < NE; ++i) {
    int n = cnt[i];
    int tl = (n + 255) >> 8;
    if (slot < tacc + tl) { e = i; lt = slot - tacc; ne = n; hb = base; return 1; }
    tacc += tl; base += tl << 8;
  }
  return 0;
}

// ===================== 256x256x64 8-phase GEMM body =========================
#define STG_A(qa, kt, b) do { \
    gload16(pA##qa##0 + (size_t)(kt) * 64, ldsp + (b) * 65536 + dA + (qa) * 8192); \
    gload16(pA##qa##1 + (size_t)(kt) * 64, ldsp + (b) * 65536 + dA + (qa) * 8192 + 16384); \
  } while (0)
#define STG_B(qb, kt, b) do { \
    gload16(pB##qb##0 + (size_t)(kt) * 64, ldsp + (b) * 65536 + 32768 + dB + (qb) * 4096); \
    gload16(pB##qb##1 + (size_t)(kt) * 64, ldsp + (b) * 65536 + 32768 + dB + (qb) * 4096 + 16384); \
  } while (0)

#define GEMM_BODY(NTILES)                                                        \
  f32x4 acc[8][4] = {};                                                          \
  frag_ab a[4][2], bb[4][2];                                                     \
  const int NT = (NTILES);                                                       \
  STG_A(0, 0, 0); STG_B(0, 0, 0); STG_B(1, 0, 0); STG_A(1, 0, 0);                \
  STG_A(0, 1, 1); STG_B(0, 1, 1); STG_B(1, 1, 1);                                \
  waitv(6); BARRIER;                                                             \
  for (int t = 0; t < NT; ++t) {                                                 \
    const char* AB = ldsp + (t & 1) * 65536;                                     \
    _Pragma("unroll") for (int i = 0; i < 4; ++i) {                              \
      a[i][0] = *(const frag_ab*)(AB + aoff + i * 2048 + xs0);                   \
      a[i][1] = *(const frag_ab*)(AB + aoff + i * 2048 + xs1);                   \
    }                                                                            \
    _Pragma("unroll") for (int j = 0; j < 2; ++j) {                              \
      bb[j][0] = *(const frag_ab*)(AB + boff + j * 2048 + xs0);                  \
      bb[j][1] = *(const frag_ab*)(AB + boff + j * 2048 + xs1);                  \
    }                                                                            \
    if (t + 1 < NT) STG_A(1, t + 1, (t + 1) & 1);                                \
    BARRIER;                                                                     \
    __builtin_amdgcn_s_setprio(1);                                               \
    _Pragma("unroll") for (int i = 0; i < 4; ++i)                                \
      _Pragma("unroll") for (int j = 0; j < 2; ++j) {                            \
        acc[i][j] = __builtin_amdgcn_mfma_f32_16x16x32_bf16(a[i][0], bb[j][0], acc[i][j], 0, 0, 0); \
        acc[i][j] = __builtin_amdgcn_mfma_f32_16x16x32_bf16(a[i][1], bb[j][1], acc[i][j], 0, 0, 0); \
      }                                                                          \
    __builtin_amdgcn_s_setprio(0);                                               \
    BARRIER;                                                                     \
    _Pragma("unroll") for (int j = 0; j < 2; ++j) {                              \
      bb[2 + j][0] = *(const frag_ab*)(AB + boff + (2 + j) * 2048 + xs0);        \
      bb[2 + j][1] = *(const frag_ab*)(AB + boff + (2 + j) * 2048 + xs1);        \
    }                                                                            \
    if (t + 2 < NT) STG_A(0, t + 2, t & 1);                                      \
    BARRIER;                                                                     \
    __builtin_amdgcn_s_setprio(1);                                               \
    _Pragma("unroll") for (int i = 0; i < 4; ++i)                                \
      _Pragma("unroll") for (int j = 0; j < 2; ++j) {                            \
        acc[i][2 + j] = __builtin_amdgcn_mfma_f32_16x16x32_bf16(a[i][0], bb[2 + j][0], acc[i][2 + j], 0, 0, 0); \
        acc[i][2 + j] = __builtin_amdgcn_mfma_f32_16x16x32_bf16(a[i][1], bb[2 + j][1], acc[i][2 + j], 0, 0, 0); \
      }                                                                          \
    __builtin_amdgcn_s_setprio(0);                                               \
    BARRIER;                                                                     \
    _Pragma("unroll") for (int i = 0; i < 4; ++i) {                              \
      a[i][0] = *(const frag_ab*)(AB + aoff + 8192 + i * 2048 + xs0);            \
      a[i][1] = *(const frag_ab*)(AB + aoff + 8192 + i * 2048 + xs1);            \
    }                                                                            \
    if (t + 2 < NT) STG_B(0, t + 2, t & 1);                                      \
    BARRIER;                                                                     \
    __builtin_amdgcn_s_setprio(1);                                               \
    _Pragma("unroll") for (int i = 0; i < 4; ++i)                                \
      _Pragma("unroll") for (int j = 0; j < 2; ++j) {                            \
        acc[4 + i][2 + j] = __builtin_amdgcn_mfma_f32_16x16x32_bf16(a[i][0], bb[2 + j][0], acc[4 + i][2 + j], 0, 0, 0); \
        acc[4 + i][2 + j] = __builtin_amdgcn_mfma_f32_16x16x32_bf16(a[i][1], bb[2 + j][1], acc[4 + i][2 + j], 0, 0, 0); \
      }                                                                          \
    __builtin_amdgcn_s_setprio(0);                                               \
    BARRIER;                                                                     \
    if (t + 2 < NT) STG_B(1, t + 2, t & 1);                                      \
    BARRIER;                                                                     \
    __builtin_amdgcn_s_setprio(1);                                               \
    _Pragma("unroll") for (int i = 0; i < 4; ++i)                                \
      _Pragma("unroll") for (int j = 0; j < 2; ++j) {                            \
        acc[4 + i][j] = __builtin_amdgcn_mfma_f32_16x16x32_bf16(a[i][0], bb[j][0], acc[4 + i][j], 0, 0, 0); \
        acc[4 + i][j] = __builtin_amdgcn_mfma_f32_16x16x32_bf16(a[i][1], bb[j][1], acc[4 + i][j], 0, 0, 0); \
      }                                                                          \
    __builtin_amdgcn_s_setprio(0);                                               \
    waitv((t + 2 < NT) ? 6 : 0);                                                 \
    BARRIER;                                                                     \
  }

// ---------------- GEMM1: H = gelu(gather(xb) @ w1t[e]^T + b1[e]) ------------
// XCD-grouped mapping: xcd = bid&7; token-tile tt = xcd + 8*(slot>>4),
// n-tile = slot&15 -> all 16 n-tiles of a tt on ONE XCD (A panel L2-shared).
__global__ __launch_bounds__(512, 2) void gemm1_kernel(
    const unsigned short* __restrict__ xb, const unsigned short* __restrict__ w1t,
    const float* __restrict__ b1, const int* __restrict__ cnt, const int* __restrict__ tok,
    unsigned short* __restrict__ H) {
  __shared__ __align__(16) char lds[131072];
  int bid = blockIdx.x;
  int s = bid >> 3;
  int tt = (bid & 7) + 8 * (s >> 4);
  int e, lt, ne, hb;
  if (!find_tile256(cnt, tt, e, lt, ne, hb)) return;
  char* ldsp = (char*)lds;
  const int tid = threadIdx.x;
  const int lane = tid & 63, w = tid >> 6;
  const int wm = w >> 2, wn = w & 3;
  const int r16 = lane & 15, kg = lane >> 4;
  const int n0 = (s & 15) * 256;

  const int xs0 = (kg ^ (r16 & 7)) * 16;
  const int xs1 = ((4 + kg) ^ (r16 & 7)) * 16;
  const int aoff = (wm * 128 + r16) * 128;
  const int boff = 32768 + (wn * 64 + r16) * 128;

  const int v = w * 8 + (lane >> 3);
  const int c8off = ((lane & 7) ^ ((lane >> 3) & 7)) * 8;
  const int dA = w * 1024;
  const int dB = (w & 3) * 1024 + (w >> 2) * 8192;
  const int tokbase = e * T_TOK;
  int rA00 = v, rA01 = v + 128, rA10 = 64 + v, rA11 = 192 + v;
  int g00 = lt * 256 + rA00, g01 = lt * 256 + rA01, g10 = lt * 256 + rA10, g11 = lt * 256 + rA11;
  int tk00 = tok[tokbase + ((g00 < ne) ? g00 : 0)];
  int tk01 = tok[tokbase + ((g01 < ne) ? g01 : 0)];
  int tk10 = tok[tokbase + ((g10 < ne) ? g10 : 0)];
  int tk11 = tok[tokbase + ((g11 < ne) ? g11 : 0)];
  const unsigned short* pA00 = xb + (size_t)tk00 * D_MODEL + c8off;
  const unsigned short* pA01 = xb + (size_t)tk01 * D_MODEL + c8off;
  const unsigned short* pA10 = xb + (size_t)tk10 * D_MODEL + c8off;
  const unsigned short* pA11 = xb + (size_t)tk11 * D_MODEL + c8off;
  int rB00 = (v & 31) + (v >> 5) * 64;
  int rB01 = rB00 + 128, rB10 = rB00 + 32, rB11 = rB00 + 160;
  const unsigned short* pB00 = w1t + ((size_t)e * D_FF + n0 + rB00) * D_MODEL + c8off;
  const unsigned short* pB01 = w1t + ((size_t)e * D_FF + n0 + rB01) * D_MODEL + c8off;
  const unsigned short* pB10 = w1t + ((size_t)e * D_FF + n0 + rB10) * D_MODEL + c8off;
  const unsigned short* pB11 = w1t + ((size_t)e * D_FF + n0 + rB11) * D_MODEL + c8off;

  GEMM_BODY(D_MODEL / 64)

  // epilogue: bias + gelu -> bf16, LDS transpose (chunk-XOR), nt vector stores
  unsigned short (*hlds)[272] = (unsigned short (*)[272])ldsp;
  float b1v[4];
#pragma unroll
  for (int j = 0; j < 4; ++j)
    b1v[j] = b1[e * D_FF + n0 + wn * 64 + j * 16 + r16];
#pragma unroll
  for (int ih = 0; ih < 2; ++ih) {
    if (ih) BARRIER;
#pragma unroll
    for (int i2 = 0; i2 < 4; ++i2)
#pragma unroll
      for (int jj = 0; jj < 4; ++jj) {
        int rl = wm * 64 + i2 * 16 + kg * 4 + jj;
#pragma unroll
        for (int j = 0; j < 4; ++j) {
          int col = wn * 64 + j * 16 + r16;
          int pos = (((col >> 3) ^ (rl & 7)) << 3) | (col & 7);
          hlds[rl][pos] = f2bf(gelu_f(acc[ih * 4 + i2][j][jj] + b1v[j]));
        }
      }
    BARRIER;
    int lrow = tid >> 2, cq = tid & 3;
    int grow = (lrow >> 6) * 128 + ih * 64 + (lrow & 63);
    unsigned short* hdst = H + (size_t)(hb + lt * 256 + grow) * D_FF + n0 + cq * 8;
#pragma unroll
    for (int c = 0; c < 8; ++c) {
      int k = cq + c * 4;
      ushort8 vv = *(const ushort8*)&hlds[lrow][(k ^ (lrow & 7)) << 3];
      __builtin_nontemporal_store(vv, (ushort8*)(hdst + c * 32));
    }
  }
}

// ---------------- GEMM2: Y = H @ w2t[e]^T + b2[e], bf16, no atomics ---------
// XCD-grouped: the 4 n-tiles of a token-tile on one XCD -> H panel read once.
__global__ __launch_bounds__(512, 2) void gemm2_kernel(
    const unsigned short* __restrict__ H, const unsigned short* __restrict__ w2t,
    const float* __restrict__ b2, const int* __restrict__ cnt,
    unsigned short* __restrict__ Y) {
  __shared__ __align__(16) char lds[131072];
  int bid = blockIdx.x;
  int s = bid >> 3;
  int tt = (bid & 7) + 8 * (s >> 2);
  int e, lt, ne, hb;
  if (!find_tile256(cnt, tt, e, lt, ne, hb)) return;
  char* ldsp = (char*)lds;
  const int tid = threadIdx.x;
  const int lane = tid & 63, w = tid >> 6;
  const int wm = w >> 2, wn = w & 3;
  const int r16 = lane & 15, kg = lane >> 4;
  const int n0 = (s & 3) * 256;

  const int xs0 = (kg ^ (r16 & 7)) * 16;
  const int xs1 = ((4 + kg) ^ (r16 & 7)) * 16;
  const int aoff = (wm * 128 + r16) * 128;
  const int boff = 32768 + (wn * 64 + r16) * 128;

  const int v = w * 8 + (lane >> 3);
  const int c8off = ((lane & 7) ^ ((lane >> 3) & 7)) * 8;
  const int dA = w * 1024;
  const int dB = (w & 3) * 1024 + (w >> 2) * 8192;
  int rA00 = v, rA01 = v + 128, rA10 = 64 + v, rA11 = 192 + v;
  const unsigned short* pA00 = H + (size_t)(hb + lt * 256 + rA00) * D_FF + c8off;
  const unsigned short* pA01 = H + (size_t)(hb + lt * 256 + rA01) * D_FF + c8off;
  const unsigned short* pA10 = H + (size_t)(hb + lt * 256 + rA10) * D_FF + c8off;
  const unsigned short* pA11 = H + (size_t)(hb + lt * 256 + rA11) * D_FF + c8off;
  int rB00 = (v & 31) + (v >> 5) * 64;
  int rB01 = rB00 + 128, rB10 = rB00 + 32, rB11 = rB00 + 160;
  const unsigned short* pB00 = w2t + ((size_t)e * D_MODEL + n0 + rB00) * D_FF + c8off;
  const unsigned short* pB01 = w2t + ((size_t)e * D_MODEL + n0 + rB01) * D_FF + c8off;
  const unsigned short* pB10 = w2t + ((size_t)e * D_MODEL + n0 + rB10) * D_FF + c8off;
  const unsigned short* pB11 = w2t + ((size_t)e * D_MODEL + n0 + rB11) * D_FF + c8off;

  GEMM_BODY(D_FF / 64)

  // epilogue: bias -> bf16 Y, LDS transpose, nt vector stores
  unsigned short (*hlds)[272] = (unsigned short (*)[272])ldsp;
  float b2v[4];
#pragma unroll
  for (int j = 0; j < 4; ++j)
    b2v[j] = b2[e * D_MODEL + n0 + wn * 64 + j * 16 + r16];
#pragma unroll
  for (int ih = 0; ih < 2; ++ih) {
    if (ih) BARRIER;
#pragma unroll
    for (int i2 = 0; i2 < 4; ++i2)
#pragma unroll
      for (int jj = 0; jj < 4; ++jj) {
        int rl = wm * 64 + i2 * 16 + kg * 4 + jj;
#pragma unroll
        for (int j = 0; j < 4; ++j) {
          int col = wn * 64 + j * 16 + r16;
          int pos = (((col >> 3) ^ (rl & 7)) << 3) | (col & 7);
          hlds[rl][pos] = f2bf(acc[ih * 4 + i2][j][jj] + b2v[j]);
        }
      }
    BARRIER;
    int lrow = tid >> 2, cq = tid & 3;
    int grow = (lrow >> 6) * 128 + ih * 64 + (lrow & 63);
    unsigned short* ydst = Y + (size_t)(hb + lt * 256 + grow) * D_MODEL + n0 + cq * 8;
#pragma unroll
    for (int c = 0; c < 8; ++c) {
      int k = cq + c * 4;
      ushort8 vv = *(const ushort8*)&hlds[lrow][(k ^ (lrow & 7)) << 3];
      __builtin_nontemporal_store(vv, (ushort8*)(ydst + c * 32));
    }
  }
}

// ---------------- Combine: out[t] = g0*Y[slot0] + g1*Y[slot1] ---------------
__global__ __launch_bounds__(256) void combine_kernel(
    const unsigned short* __restrict__ Y, const int* __restrict__ cnt,
    const int* __restrict__ mi, const float* __restrict__ mg,
    float* __restrict__ out) {
  int w = threadIdx.x >> 6, lane = threadIdx.x & 63;
  int t = blockIdx.x * 4 + w;
  int e0 = mi[4 * t], e1 = mi[4 * t + 1], p0 = mi[4 * t + 2], p1 = mi[4 * t + 3];
  float g0 = mg[2 * t], g1 = mg[2 * t + 1];
  int hbA = 0, hbB = 0, accv = 0;
#pragma unroll
  for (int e = 0; e < NE; ++e) {
    if (e == e0) hbA = accv;
    if (e == e1) hbB = accv;
    accv += (cnt[e] + 255) & ~255;
  }
  const unsigned short* ra = Y + (size_t)(hbA + p0) * D_MODEL;
  const unsigned short* rb = Y + (size_t)(hbB + p1) * D_MODEL;
  float* orow = out + (size_t)t * D_MODEL;
#pragma unroll
  for (int it = 0; it < 4; ++it) {
    int c = it * 256 + lane * 4;
    ushort4v va = *(const ushort4v*)(ra + c);
    ushort4v vb = *(const ushort4v*)(rb + c);
    f32x4 o;
#pragma unroll
    for (int k = 0; k < 4; ++k) o[k] = g0 * bf2f(va[k]) + g1 * bf2f(vb[k]);
    *(f32x4*)(orow + c) = o;
  }
}

extern "C" void kernel_launch(void* const* d_in, const int* in_sizes, int n_in,
                              void* d_out, int out_size, void* d_ws, size_t ws_size,
                              hipStream_t stream) {
  const float* x  = (const float*)d_in[0];
  const float* rw = (const float*)d_in[1];
  const float* rb = (const float*)d_in[2];
  const float* w1 = (const float*)d_in[3];
  const float* b1 = (const float*)d_in[4];
  const float* w2 = (const float*)d_in[5];
  const float* b2 = (const float*)d_in[6];
  float* out = (float*)d_out;
  char* ws = (char*)d_ws;

  int*   cnt = (int*)ws;                                   // 256 B
  int*   tok = (int*)(ws + 256);                           // 512 KB
  int*   mi  = (int*)(ws + 256 + 524288);                  // 256 KB
  float* mg  = (float*)(ws + 256 + 524288 + 262144);       // 128 KB

  // big buffers: xb 33.5MB | w1t 64MB | w2t 64MB | H 285MB ; Y overlaps xb/w1t
  unsigned short* xb  = (unsigned short*)(ws + HOFF);
  unsigned short* w1t = (unsigned short*)(ws + HOFF + 33554432u);
  unsigned short* w2t = (unsigned short*)(ws + HOFF + 33554432u + 67108864u);
  unsigned short* H   = (unsigned short*)(ws + HOFF + 33554432u + 67108864u + 67108864u);
  unsigned short* Y   = (unsigned short*)(ws + HOFF);

  hipMemsetAsync(cnt, 0, 64, stream);
  router_kernel<<<dim3(T_TOK / 64), dim3(256), 0, stream>>>(x, rw, rb, cnt, tok, mi, mg, xb);
  transpose_cvt_kernel<<<dim3(D_FF / 64, D_MODEL / 64, NE), dim3(256), 0, stream>>>(w1, w1t, D_MODEL, D_FF);
  transpose_cvt_kernel<<<dim3(D_MODEL / 64, D_FF / 64, NE), dim3(256), 0, stream>>>(w2, w2t, D_FF, D_MODEL);
  // grids: 8 XCD groups x 17 token-tile slots x n-tiles
  gemm1_kernel<<<dim3(8 * 17 * 16), dim3(512), 0, stream>>>(xb, w1t, b1, cnt, tok, H);
  gemm2_kernel<<<dim3(8 * 17 * 4), dim3(512), 0, stream>>>(H, w2t, b2, cnt, Y);
  combine_kernel<<<dim3(T_TOK / 4), dim3(256), 0, stream>>>(Y, cnt, mi, mg, out);
}